// Round 7
// baseline (416.965 us; speedup 1.0000x reference)
//
#include <hip/hip_runtime.h>
#include <hip/hip_bf16.h>
#include <stdint.h>

#define B_ 2
#define T_ 2048
#define HID_ 2048
#define H_ 16
#define KVH_ 4
#define D_ 128

typedef __attribute__((ext_vector_type(8))) short short8;
typedef __attribute__((ext_vector_type(4))) float f32x4;

__device__ __forceinline__ uint16_t f2bf(float x) {
  union { float f; uint32_t u; } c; c.f = x;
  uint32_t r = c.u + 0x7fffu + ((c.u >> 16) & 1u);
  return (uint16_t)(r >> 16);
}
__device__ __forceinline__ float bf2f(uint16_t b) {
  union { uint32_t u; float f; } c; c.u = ((uint32_t)b) << 16;
  return c.f;
}
__device__ __forceinline__ uint16_t hwbf(float x) {
  __hip_bfloat16 h = __float2bfloat16(x);
  return *reinterpret_cast<uint16_t*>(&h);
}

// ---------------- fp32 -> bf16 convert ----------------
__global__ __launch_bounds__(256) void cvt_f32_bf16(const float* __restrict__ in,
                                                    uint16_t* __restrict__ out, int n) {
  int i = (blockIdx.x * 256 + threadIdx.x) * 4;
  if (i >= n) return;
  const float4 v = *reinterpret_cast<const float4*>(in + i);
  union { uint16_t s[4]; uint2 u; } pk;
  pk.s[0] = f2bf(v.x); pk.s[1] = f2bf(v.y); pk.s[2] = f2bf(v.z); pk.s[3] = f2bf(v.w);
  *reinterpret_cast<uint2*>(out + i) = pk.u;
}

__global__ __launch_bounds__(256) void concat_bias(const float* __restrict__ bq,
                                                   const float* __restrict__ bk,
                                                   const float* __restrict__ bv,
                                                   float* __restrict__ out) {
  int i = blockIdx.x * 256 + threadIdx.x;
  if (i < 2048) out[i] = bq[i];
  else if (i < 2560) out[i] = bk[i - 2048];
  else if (i < 3072) out[i] = bv[i - 2560];
}

// ---------------- bt-GEMM: A[M][K] bf16, Bt[N][K] bf16 -> C[M][N] ----------------
#define BM 128
#define BN 128
#define BK 64

template<bool OUT_F32, bool HAS_BIAS>
__global__ __launch_bounds__(256) void gemm_bt(const uint16_t* __restrict__ A,
                                               const uint16_t* __restrict__ Bt,
                                               void* __restrict__ Cv,
                                               const float* __restrict__ bias,
                                               int M, int N, int K) {
  __shared__ __align__(16) uint16_t Al[BM * BK];
  __shared__ __align__(16) uint16_t Bl[BN * BK];
  const int tid = threadIdx.x;
  const int w = tid >> 6;
  const int lane = tid & 63;
  const int wr = w >> 1, wc = w & 1;
  const int bm = blockIdx.y * BM;
  const int bn = blockIdx.x * BN;
  const int lm = lane & 15, lg = lane >> 4;
  const int srow = lane >> 3, scol = (lane & 7) * 8;

  f32x4 acc[4][4];
  const f32x4 z4 = {0.f, 0.f, 0.f, 0.f};
#pragma unroll
  for (int i = 0; i < 4; ++i)
#pragma unroll
    for (int j = 0; j < 4; ++j) acc[i][j] = z4;

  for (int k0 = 0; k0 < K; k0 += BK) {
#pragma unroll
    for (int i = 0; i < 4; ++i) {
      const int c = i * 4 + w;
      const int row = c * 8 + srow;
      const uint16_t* gA = A + (size_t)(bm + row) * K + k0 + scol;
      const uint16_t* gB = Bt + (size_t)(bn + row) * K + k0 + scol;
      __builtin_amdgcn_global_load_lds((const __attribute__((address_space(1))) unsigned int*)gA,
                                       (__attribute__((address_space(3))) unsigned int*)(Al + c * 512),
                                       16, 0, 0);
      __builtin_amdgcn_global_load_lds((const __attribute__((address_space(1))) unsigned int*)gB,
                                       (__attribute__((address_space(3))) unsigned int*)(Bl + c * 512),
                                       16, 0, 0);
    }
    __syncthreads();
#pragma unroll
    for (int kk = 0; kk < 2; ++kk) {
      const int ko = kk * 32 + lg * 8;
      short8 af[4], bfr[4];
#pragma unroll
      for (int mi = 0; mi < 4; ++mi)
        af[mi] = *reinterpret_cast<const short8*>(Al + (wr * 64 + mi * 16 + lm) * BK + ko);
#pragma unroll
      for (int ni = 0; ni < 4; ++ni)
        bfr[ni] = *reinterpret_cast<const short8*>(Bl + (wc * 64 + ni * 16 + lm) * BK + ko);
#pragma unroll
      for (int mi = 0; mi < 4; ++mi)
#pragma unroll
        for (int ni = 0; ni < 4; ++ni)
          acc[mi][ni] = __builtin_amdgcn_mfma_f32_16x16x32_bf16(af[mi], bfr[ni], acc[mi][ni], 0, 0, 0);
    }
    __syncthreads();
  }

#pragma unroll
  for (int mi = 0; mi < 4; ++mi) {
#pragma unroll
    for (int ni = 0; ni < 4; ++ni) {
      const int col = bn + wc * 64 + ni * 16 + lm;
      float bb = 0.f;
      if (HAS_BIAS) bb = bias[col];
#pragma unroll
      for (int r = 0; r < 4; ++r) {
        const int row = bm + wr * 64 + mi * 16 + lg * 4 + r;
        const float v = acc[mi][ni][r] + bb;
        if (OUT_F32) reinterpret_cast<float*>(Cv)[(size_t)row * N + col] = v;
        else reinterpret_cast<uint16_t*>(Cv)[(size_t)row * N + col] = f2bf(v);
      }
    }
  }
}

// ---------------- RoPE + scatter, vectorized (Q scaled by 1/sqrt(D)*log2e) ----------------
#define SC_Q 0.1275523865396698f  // 0.08838834764831845 * 1.44269504088896341

__global__ __launch_bounds__(320) void rope_scatter(const uint16_t* __restrict__ raw,
                                                    const float* __restrict__ cosp,
                                                    const float* __restrict__ sinp,
                                                    uint16_t* __restrict__ Qo,
                                                    uint16_t* __restrict__ Ko) {
  const int c8 = threadIdx.x;            // 0..319 (chunk of 8 elems)
  const int m = blockIdx.x;              // 0..4095
  const int b = m >> 11, tt = m & 2047;
  const int c = c8 * 8;                  // 0..2552
  const int d = c & 127;
  const size_t rowoff = (size_t)m * 3072;
  union { short8 v; uint16_t s[8]; } x8, p8, o8;
  x8.v = *reinterpret_cast<const short8*>(raw + rowoff + c);
  p8.v = *reinterpret_cast<const short8*>(raw + rowoff + (c ^ 64));
  const float* cb = cosp + ((size_t)b * T_ + tt) * D_ + d;
  const float* sb = sinp + ((size_t)b * T_ + tt) * D_ + d;
  const bool isq = (c < 2048);
  const float scale = isq ? SC_Q : 1.0f;
  const float sgn = (d < 64) ? -1.f : 1.f;
#pragma unroll
  for (int j = 0; j < 8; ++j) {
    const float x = bf2f(x8.s[j]);
    const float px = bf2f(p8.s[j]);
    o8.s[j] = f2bf((x * cb[j] + sgn * px * sb[j]) * scale);
  }
  if (isq) {
    const int hh = c >> 7;
    *reinterpret_cast<short8*>(Qo + (((size_t)(b * H_ + hh)) * T_ + tt) * D_ + d) = o8.v;
  } else {
    const int hh = (c - 2048) >> 7;
    *reinterpret_cast<short8*>(Ko + (((size_t)(b * KVH_ + hh)) * T_ + tt) * D_ + d) = o8.v;
  }
}

// ---------------- V transpose: qkvraw cols 2560..3071 -> VtG[b][kvh][d][t] ----------------
__global__ __launch_bounds__(256) void transpose_v(const uint16_t* __restrict__ raw,
                                                   uint16_t* __restrict__ VtG) {
  const int hb = blockIdx.y;            // b*4+kvh, 0..7
  const int b = hb >> 2, kvh = hb & 3;
  const int d = threadIdx.x & 127;
  const int tw = threadIdx.x >> 7;      // 0..1
  const int t0 = blockIdx.x * 16 + tw * 8;
  const uint16_t* src = raw + ((size_t)(b * T_ + t0)) * 3072 + 2560 + kvh * 128 + d;
  union { uint16_t s[8]; short8 v; } pk;
#pragma unroll
  for (int j = 0; j < 8; ++j) pk.s[j] = src[(size_t)j * 3072];
  *reinterpret_cast<short8*>(VtG + ((size_t)hb * D_ + d) * T_ + t0) = pk.v;
}

// ---------------- causal GQA flash attention ----------------
// QBLK=64 (16 q-rows/wave), KVBLK=64, 1024 blocks all-resident at 4 blk/CU.
// LDS linear + chunk-XOR swizzle XM(row) = (row&7)^((row>>1)&4):
//   staging applies XM to the GLOBAL source chunk (gload_lds dest stays linear),
//   reads/P-writes apply XM to the LDS chunk index. 40960 B total.
#define KVBLK 64
#define XM(r) (((r) & 7) ^ (((r) >> 1) & 4))

__global__ __launch_bounds__(256, 4) void attn_fwd(const uint16_t* __restrict__ Qb,
                                                   const uint16_t* __restrict__ Kb,
                                                   const uint16_t* __restrict__ VtG,
                                                   uint16_t* __restrict__ Ab) {
  __shared__ __align__(16) uint16_t Kl[KVBLK * D_];     // 16384 B
  __shared__ __align__(16) uint16_t Vtl[D_ * KVBLK];    // 16384 B
  __shared__ __align__(16) uint16_t Pl[4 * 16 * 64];    //  8192 B  (total 40960 -> 4 blk/CU)
  const int tid = threadIdx.x;
  const int w = tid >> 6, lane = tid & 63;
  const int lm = lane & 15, lg = lane >> 4;
  const int bh = blockIdx.y;
  const int b = bh >> 4, h = bh & 15;
  const int kvh = h >> 2;
  const int qt = (blockIdx.x + bh) & 31;  // load-balance swizzle, 32 q-tiles of 64
  const int q0 = qt * 64;
  const int wrow0 = q0 + w * 16;          // this wave's first q-row

  // Q fragments (A-frag: m=lane&15, k=(lane>>4)*8+j); Q pre-scaled by SC_Q
  const uint16_t* Qw = Qb + (((size_t)(b * H_ + h)) * T_ + wrow0) * D_;
  short8 qf[4];
#pragma unroll
  for (int kk = 0; kk < 4; ++kk)
    qf[kk] = *reinterpret_cast<const short8*>(Qw + (size_t)lm * D_ + kk * 32 + lg * 8);

  f32x4 o[8];
  const f32x4 z4 = {0.f, 0.f, 0.f, 0.f};
#pragma unroll
  for (int f = 0; f < 8; ++f) o[f] = z4;
  float mrow[4] = {-1e30f, -1e30f, -1e30f, -1e30f};
  float lrow[4] = {0.f, 0.f, 0.f, 0.f};

  const uint16_t* Kbase = Kb + ((size_t)(b * KVH_ + kvh)) * T_ * D_;
  const uint16_t* Vtbase = VtG + ((size_t)(b * KVH_ + kvh)) * D_ * T_;
  uint16_t* Pw = Pl + w * 16 * 64;

  const int nkv = 2 * qt + 2;
  for (int t = 0; t < nkv; ++t) {
    const int kv0 = t * KVBLK;
    __syncthreads();  // prior tile's LDS reads done before restage
    // stage K [64 rows][16 chunks] and Vt [128 rows][8 chunks] via global_load_lds;
    // LDS dest linear in chunk id, global source column-chunk XOR-swizzled.
#pragma unroll
    for (int it = 0; it < 4; ++it) {
      const int chunk = it * 256 + tid;
      {
        const int r = chunk >> 4, c16 = chunk & 15;
        const uint16_t* g = Kbase + (size_t)(kv0 + r) * D_ + ((c16 ^ XM(r)) * 8);
        __builtin_amdgcn_global_load_lds((const __attribute__((address_space(1))) unsigned int*)g,
                                         (__attribute__((address_space(3))) unsigned int*)(Kl + (it * 256 + w * 64) * 8),
                                         16, 0, 0);
      }
      {
        const int dd = chunk >> 3, c8 = chunk & 7;
        const uint16_t* g = Vtbase + (size_t)dd * T_ + kv0 + ((c8 ^ XM(dd)) * 8);
        __builtin_amdgcn_global_load_lds((const __attribute__((address_space(1))) unsigned int*)g,
                                         (__attribute__((address_space(3))) unsigned int*)(Vtl + (it * 256 + w * 64) * 8),
                                         16, 0, 0);
      }
    }
    __syncthreads();

    // S = Q K^T : 4 col-frags x 4 k-frags
    f32x4 s[4];
#pragma unroll
    for (int nf = 0; nf < 4; ++nf) s[nf] = z4;
#pragma unroll
    for (int nf = 0; nf < 4; ++nf)
#pragma unroll
      for (int kk = 0; kk < 4; ++kk) {
        const int row = nf * 16 + lm;
        const short8 kf = *reinterpret_cast<const short8*>(Kl + row * D_ + (((kk * 4 + lg) ^ XM(row)) * 8));
        s[nf] = __builtin_amdgcn_mfma_f32_16x16x32_bf16(qf[kk], kf, s[nf], 0, 0, 0);
      }

    // causal mask (only on tiles this wave's rows intersect)
    if (kv0 + KVBLK - 1 > wrow0) {
#pragma unroll
      for (int nf = 0; nf < 4; ++nf) {
        const int colg = kv0 + nf * 16 + lm;
#pragma unroll
        for (int r = 0; r < 4; ++r) {
          const int rowg = wrow0 + lg * 4 + r;
          if (colg > rowg) s[nf][r] = -1e30f;
        }
      }
    }

    float tmax[4];
#pragma unroll
    for (int r = 0; r < 4; ++r) {
      float v = fmaxf(fmaxf(s[0][r], s[1][r]), fmaxf(s[2][r], s[3][r]));
      v = fmaxf(v, __shfl_xor(v, 1));
      v = fmaxf(v, __shfl_xor(v, 2));
      v = fmaxf(v, __shfl_xor(v, 4));
      v = fmaxf(v, __shfl_xor(v, 8));
      tmax[r] = v;
    }
    // defer-max: skip rescale unless tile max grew past threshold
    bool grow = false;
#pragma unroll
    for (int r = 0; r < 4; ++r) grow = grow || (tmax[r] > mrow[r] + 8.f);
    if (__any((int)grow)) {
#pragma unroll
      for (int r = 0; r < 4; ++r) {
        const float nm = fmaxf(mrow[r], tmax[r]);
        const float al = exp2f(mrow[r] - nm);
        mrow[r] = nm;
        lrow[r] *= al;
#pragma unroll
        for (int f = 0; f < 8; ++f) o[f][r] *= al;
      }
    }
    float rsum[4] = {0.f, 0.f, 0.f, 0.f};
#pragma unroll
    for (int nf = 0; nf < 4; ++nf)
#pragma unroll
      for (int r = 0; r < 4; ++r) {
        const float p = exp2f(s[nf][r] - mrow[r]);
        rsum[r] += p;
        const int prow = lg * 4 + r;
        const int pchunk = (nf * 2 + (lm >> 3)) ^ XM(prow);
        Pw[prow * 64 + pchunk * 8 + (lm & 7)] = hwbf(p);
      }
#pragma unroll
    for (int r = 0; r < 4; ++r) {
      float v = rsum[r];
      v += __shfl_xor(v, 1);
      v += __shfl_xor(v, 2);
      v += __shfl_xor(v, 4);
      v += __shfl_xor(v, 8);
      lrow[r] += v;
    }
    // P is wave-private: drain ds_writes; no cross-wave barrier needed
    asm volatile("s_waitcnt lgkmcnt(0)" ::: "memory");
    short8 pf[2];
#pragma unroll
    for (int ks = 0; ks < 2; ++ks)
      pf[ks] = *reinterpret_cast<const short8*>(Pw + lm * 64 + (((ks * 4 + lg) ^ XM(lm)) * 8));
#pragma unroll
    for (int f = 0; f < 8; ++f)
#pragma unroll
      for (int ks = 0; ks < 2; ++ks) {
        const int dd = f * 16 + lm;
        const short8 vf = *reinterpret_cast<const short8*>(Vtl + dd * KVBLK + (((ks * 4 + lg) ^ XM(dd)) * 8));
        o[f] = __builtin_amdgcn_mfma_f32_16x16x32_bf16(pf[ks], vf, o[f], 0, 0, 0);
      }
  }

  float rcp[4];
#pragma unroll
  for (int r = 0; r < 4; ++r) rcp[r] = 1.0f / lrow[r];
#pragma unroll
  for (int f = 0; f < 8; ++f) {
    const int col = h * D_ + f * 16 + lm;
#pragma unroll
    for (int r = 0; r < 4; ++r) {
      const int trow = wrow0 + lg * 4 + r;
      Ab[((size_t)(b * T_ + trow)) * (H_ * D_) + col] = f2bf(o[f][r] * rcp[r]);
    }
  }
}

// ---------------- launch ----------------
extern "C" void kernel_launch(void* const* d_in, const int* in_sizes, int n_in,
                              void* d_out, int out_size, void* d_ws, size_t ws_size,
                              hipStream_t stream) {
  const float* hidden = (const float*)d_in[0];
  const float* cosp   = (const float*)d_in[1];
  const float* sinp   = (const float*)d_in[2];
  // d_in[3] = attention_mask: exactly causal, implemented in-kernel
  const float* Wq = (const float*)d_in[4];
  const float* bq = (const float*)d_in[5];
  const float* Wk = (const float*)d_in[6];
  const float* bk = (const float*)d_in[7];
  const float* Wv = (const float*)d_in[8];
  const float* bv = (const float*)d_in[9];
  const float* Wo = (const float*)d_in[10];

  char* ws = (char*)d_ws;
  uint16_t* hidb   = (uint16_t*)(ws);              // 4096x2048 bf16   16,777,216 B
  uint16_t* wqkv   = (uint16_t*)(ws + 16777216);   // 3072x2048 bf16   12,582,912 B
  uint16_t* wob    = (uint16_t*)(ws + 29360128);   // 2048x2048 bf16    8,388,608 B
  float*    biasq  = (float*)   (ws + 37748736);   // 3072 f32             12,288 B
  uint16_t* qkvraw = (uint16_t*)(ws + 37761024);   // 4096x3072 bf16   25,165,824 B
  uint16_t* Qb     = (uint16_t*)(ws + 62926848);   // [2][16][2048][128] 16,777,216 B
  uint16_t* Kb     = (uint16_t*)(ws + 79704064);   // [2][4][2048][128]   4,194,304 B
  uint16_t* VtG    = (uint16_t*)(ws + 83898368);   // [2][4][128][2048]   4,194,304 B
  uint16_t* Ab     = (uint16_t*)(ws + 88092672);   // [2][2048][2048]   16,777,216 B

  cvt_f32_bf16<<<8192, 256, 0, stream>>>(hidden, hidb, 8388608);
  cvt_f32_bf16<<<4096, 256, 0, stream>>>(Wq, wqkv, 4194304);
  cvt_f32_bf16<<<1024, 256, 0, stream>>>(Wk, wqkv + 4194304, 1048576);
  cvt_f32_bf16<<<1024, 256, 0, stream>>>(Wv, wqkv + 5242880, 1048576);
  cvt_f32_bf16<<<4096, 256, 0, stream>>>(Wo, wob, 4194304);
  concat_bias<<<12, 256, 0, stream>>>(bq, bk, bv, biasq);

  // QKV projection: [4096,2048] x [3072,2048]^T -> [4096,3072] (+bias)
  gemm_bt<false, true><<<dim3(24, 32), 256, 0, stream>>>(hidb, wqkv, qkvraw, biasq, 4096, 3072, 2048);
  // RoPE + scatter Q,K (Q pre-scaled by 1/sqrt(D)*log2e)
  rope_scatter<<<4096, 320, 0, stream>>>(qkvraw, cosp, sinp, Qb, Kb);
  // V transpose to [d][t]
  transpose_v<<<dim3(128, 8), 256, 0, stream>>>(qkvraw, VtG);
  // causal GQA flash attention -> Ab [b][t][h*128+d] bf16
  attn_fwd<<<dim3(32, 32), 256, 0, stream>>>(Qb, Kb, VtG, Ab);
  // output projection: [4096,2048] x [2048,2048]^T -> d_out fp32
  gemm_bt<true, false><<<dim3(16, 32), 256, 0, stream>>>(Ab, wob, d_out, nullptr, 4096, 2048, 2048);
}

// Round 9
// 269.018 us; speedup vs baseline: 1.5500x; 1.5500x over previous
//
#include <hip/hip_runtime.h>
#include <hip/hip_bf16.h>
#include <stdint.h>

#define B_ 2
#define T_ 2048
#define HID_ 2048
#define H_ 16
#define KVH_ 4
#define D_ 128

typedef __attribute__((ext_vector_type(8))) short short8;
typedef __attribute__((ext_vector_type(4))) float f32x4;

__device__ __forceinline__ uint16_t f2bf(float x) {
  union { float f; uint32_t u; } c; c.f = x;
  uint32_t r = c.u + 0x7fffu + ((c.u >> 16) & 1u);
  return (uint16_t)(r >> 16);
}
__device__ __forceinline__ float bf2f(uint16_t b) {
  union { uint32_t u; float f; } c; c.u = ((uint32_t)b) << 16;
  return c.f;
}
__device__ __forceinline__ uint16_t hwbf(float x) {
  __hip_bfloat16 h = __float2bfloat16(x);
  return *reinterpret_cast<uint16_t*>(&h);
}

// ---------------- fp32 -> bf16 convert ----------------
__global__ __launch_bounds__(256) void cvt_f32_bf16(const float* __restrict__ in,
                                                    uint16_t* __restrict__ out, int n) {
  int i = (blockIdx.x * 256 + threadIdx.x) * 4;
  if (i >= n) return;
  const float4 v = *reinterpret_cast<const float4*>(in + i);
  union { uint16_t s[4]; uint2 u; } pk;
  pk.s[0] = f2bf(v.x); pk.s[1] = f2bf(v.y); pk.s[2] = f2bf(v.z); pk.s[3] = f2bf(v.w);
  *reinterpret_cast<uint2*>(out + i) = pk.u;
}

__global__ __launch_bounds__(256) void concat_bias(const float* __restrict__ bq,
                                                   const float* __restrict__ bk,
                                                   const float* __restrict__ bv,
                                                   float* __restrict__ out) {
  int i = blockIdx.x * 256 + threadIdx.x;
  if (i < 2048) out[i] = bq[i];
  else if (i < 2560) out[i] = bk[i - 2048];
  else if (i < 3072) out[i] = bv[i - 2560];
}

// ---------------- bt-GEMM: A[M][K] bf16, Bt[N][K] bf16 -> C[M][N] ----------------
#define BM 128
#define BN 128
#define BK 64

template<bool OUT_F32, bool HAS_BIAS>
__global__ __launch_bounds__(256) void gemm_bt(const uint16_t* __restrict__ A,
                                               const uint16_t* __restrict__ Bt,
                                               void* __restrict__ Cv,
                                               const float* __restrict__ bias,
                                               int M, int N, int K) {
  __shared__ __align__(16) uint16_t Al[BM * BK];
  __shared__ __align__(16) uint16_t Bl[BN * BK];
  const int tid = threadIdx.x;
  const int w = tid >> 6;
  const int lane = tid & 63;
  const int wr = w >> 1, wc = w & 1;
  const int bm = blockIdx.y * BM;
  const int bn = blockIdx.x * BN;
  const int lm = lane & 15, lg = lane >> 4;
  const int srow = lane >> 3, scol = (lane & 7) * 8;

  f32x4 acc[4][4];
  const f32x4 z4 = {0.f, 0.f, 0.f, 0.f};
#pragma unroll
  for (int i = 0; i < 4; ++i)
#pragma unroll
    for (int j = 0; j < 4; ++j) acc[i][j] = z4;

  for (int k0 = 0; k0 < K; k0 += BK) {
#pragma unroll
    for (int i = 0; i < 4; ++i) {
      const int c = i * 4 + w;
      const int row = c * 8 + srow;
      const uint16_t* gA = A + (size_t)(bm + row) * K + k0 + scol;
      const uint16_t* gB = Bt + (size_t)(bn + row) * K + k0 + scol;
      __builtin_amdgcn_global_load_lds((const __attribute__((address_space(1))) unsigned int*)gA,
                                       (__attribute__((address_space(3))) unsigned int*)(Al + c * 512),
                                       16, 0, 0);
      __builtin_amdgcn_global_load_lds((const __attribute__((address_space(1))) unsigned int*)gB,
                                       (__attribute__((address_space(3))) unsigned int*)(Bl + c * 512),
                                       16, 0, 0);
    }
    __syncthreads();
#pragma unroll
    for (int kk = 0; kk < 2; ++kk) {
      const int ko = kk * 32 + lg * 8;
      short8 af[4], bfr[4];
#pragma unroll
      for (int mi = 0; mi < 4; ++mi)
        af[mi] = *reinterpret_cast<const short8*>(Al + (wr * 64 + mi * 16 + lm) * BK + ko);
#pragma unroll
      for (int ni = 0; ni < 4; ++ni)
        bfr[ni] = *reinterpret_cast<const short8*>(Bl + (wc * 64 + ni * 16 + lm) * BK + ko);
#pragma unroll
      for (int mi = 0; mi < 4; ++mi)
#pragma unroll
        for (int ni = 0; ni < 4; ++ni)
          acc[mi][ni] = __builtin_amdgcn_mfma_f32_16x16x32_bf16(af[mi], bfr[ni], acc[mi][ni], 0, 0, 0);
    }
    __syncthreads();
  }

#pragma unroll
  for (int mi = 0; mi < 4; ++mi) {
#pragma unroll
    for (int ni = 0; ni < 4; ++ni) {
      const int col = bn + wc * 64 + ni * 16 + lm;
      float bb = 0.f;
      if (HAS_BIAS) bb = bias[col];
#pragma unroll
      for (int r = 0; r < 4; ++r) {
        const int row = bm + wr * 64 + mi * 16 + lg * 4 + r;
        const float v = acc[mi][ni][r] + bb;
        if (OUT_F32) reinterpret_cast<float*>(Cv)[(size_t)row * N + col] = v;
        else reinterpret_cast<uint16_t*>(Cv)[(size_t)row * N + col] = f2bf(v);
      }
    }
  }
}

// ---------------- RoPE + scatter, vectorized (Q scaled by 1/sqrt(D)*log2e) ----------------
#define SC_Q 0.1275523865396698f  // 0.08838834764831845 * 1.44269504088896341

__global__ __launch_bounds__(320) void rope_scatter(const uint16_t* __restrict__ raw,
                                                    const float* __restrict__ cosp,
                                                    const float* __restrict__ sinp,
                                                    uint16_t* __restrict__ Qo,
                                                    uint16_t* __restrict__ Ko) {
  const int c8 = threadIdx.x;            // 0..319 (chunk of 8 elems)
  const int m = blockIdx.x;              // 0..4095
  const int b = m >> 11, tt = m & 2047;
  const int c = c8 * 8;                  // 0..2552
  const int d = c & 127;
  const size_t rowoff = (size_t)m * 3072;
  union { short8 v; uint16_t s[8]; } x8, p8, o8;
  x8.v = *reinterpret_cast<const short8*>(raw + rowoff + c);
  p8.v = *reinterpret_cast<const short8*>(raw + rowoff + (c ^ 64));
  const float* cb = cosp + ((size_t)b * T_ + tt) * D_ + d;
  const float* sb = sinp + ((size_t)b * T_ + tt) * D_ + d;
  const bool isq = (c < 2048);
  const float scale = isq ? SC_Q : 1.0f;
  const float sgn = (d < 64) ? -1.f : 1.f;
#pragma unroll
  for (int j = 0; j < 8; ++j) {
    const float x = bf2f(x8.s[j]);
    const float px = bf2f(p8.s[j]);
    o8.s[j] = f2bf((x * cb[j] + sgn * px * sb[j]) * scale);
  }
  if (isq) {
    const int hh = c >> 7;
    *reinterpret_cast<short8*>(Qo + (((size_t)(b * H_ + hh)) * T_ + tt) * D_ + d) = o8.v;
  } else {
    const int hh = (c - 2048) >> 7;
    *reinterpret_cast<short8*>(Ko + (((size_t)(b * KVH_ + hh)) * T_ + tt) * D_ + d) = o8.v;
  }
}

// ---------------- V transpose: qkvraw cols 2560..3071 -> VtG[b][kvh][d][t] ----------------
__global__ __launch_bounds__(256) void transpose_v(const uint16_t* __restrict__ raw,
                                                   uint16_t* __restrict__ VtG) {
  const int hb = blockIdx.y;            // b*4+kvh, 0..7
  const int b = hb >> 2, kvh = hb & 3;
  const int d = threadIdx.x & 127;
  const int tw = threadIdx.x >> 7;      // 0..1
  const int t0 = blockIdx.x * 16 + tw * 8;
  const uint16_t* src = raw + ((size_t)(b * T_ + t0)) * 3072 + 2560 + kvh * 128 + d;
  union { uint16_t s[8]; short8 v; } pk;
#pragma unroll
  for (int j = 0; j < 8; ++j) pk.s[j] = src[(size_t)j * 3072];
  *reinterpret_cast<short8*>(VtG + ((size_t)hb * D_ + d) * T_ + t0) = pk.v;
}

// ---------------- causal GQA flash attention ----------------
// QBLK=64 (16 q-rows/wave), KVBLK=64, 1024 blocks all-resident at 4 blk/CU.
// LDS linear + chunk-XOR swizzle XM(row); staging swizzles the GLOBAL source
// chunk (gload_lds dest linear), reads/P-writes swizzle the LDS chunk index.
// Row-sum denominator via ones-column MFMA (no rsum shuffle); tmax shuffle
// reduce only when the defer-max threshold trips (rare after tile 0).
#define KVBLK 64
#define XM(r) (((r) & 7) ^ (((r) >> 1) & 4))

__global__ __launch_bounds__(256, 4) void attn_fwd(const uint16_t* __restrict__ Qb,
                                                   const uint16_t* __restrict__ Kb,
                                                   const uint16_t* __restrict__ VtG,
                                                   uint16_t* __restrict__ Ab) {
  __shared__ __align__(16) uint16_t Kl[KVBLK * D_];     // 16384 B
  __shared__ __align__(16) uint16_t Vtl[D_ * KVBLK];    // 16384 B
  __shared__ __align__(16) uint16_t Pl[4 * 16 * 64];    //  8192 B  (total 40960 -> 4 blk/CU)
  const int tid = threadIdx.x;
  const int w = tid >> 6, lane = tid & 63;
  const int lm = lane & 15, lg = lane >> 4;
  const int bh = blockIdx.y;
  const int b = bh >> 4, h = bh & 15;
  const int kvh = h >> 2;
  const int qt = (blockIdx.x + bh) & 31;  // load-balance swizzle, 32 q-tiles of 64
  const int q0 = qt * 64;
  const int wrow0 = q0 + w * 16;          // this wave's first q-row

  // Q fragments (A-frag: m=lane&15, k=(lane>>4)*8+j); Q pre-scaled by SC_Q
  const uint16_t* Qw = Qb + (((size_t)(b * H_ + h)) * T_ + wrow0) * D_;
  short8 qf[4];
#pragma unroll
  for (int kk = 0; kk < 4; ++kk)
    qf[kk] = *reinterpret_cast<const short8*>(Qw + (size_t)lm * D_ + kk * 32 + lg * 8);

  f32x4 o[8];
  const f32x4 z4 = {0.f, 0.f, 0.f, 0.f};
#pragma unroll
  for (int f = 0; f < 8; ++f) o[f] = z4;
  f32x4 osum = z4;                         // row-sum accumulator (ones-column MFMA)
  float mrow[4] = {-1e30f, -1e30f, -1e30f, -1e30f};
  short8 vone;
#pragma unroll
  for (int j = 0; j < 8; ++j) vone[j] = (short)0x3F80;  // bf16 1.0

  const uint16_t* Kbase = Kb + ((size_t)(b * KVH_ + kvh)) * T_ * D_;
  const uint16_t* Vtbase = VtG + ((size_t)(b * KVH_ + kvh)) * D_ * T_;
  uint16_t* Pw = Pl + w * 16 * 64;

  const int nkv = qt + 1;   // exact causal KV range for this q-tile
  for (int t = 0; t < nkv; ++t) {
    const int kv0 = t * KVBLK;
    __syncthreads();  // prior tile's LDS reads done before restage
    // stage K [64 rows][16 chunks] and Vt [128 rows][8 chunks] via global_load_lds;
    // LDS dest linear in chunk id, global source column-chunk XOR-swizzled.
#pragma unroll
    for (int it = 0; it < 4; ++it) {
      const int chunk = it * 256 + tid;
      {
        const int r = chunk >> 4, c16 = chunk & 15;
        const uint16_t* g = Kbase + (size_t)(kv0 + r) * D_ + ((c16 ^ XM(r)) * 8);
        __builtin_amdgcn_global_load_lds((const __attribute__((address_space(1))) unsigned int*)g,
                                         (__attribute__((address_space(3))) unsigned int*)(Kl + (it * 256 + w * 64) * 8),
                                         16, 0, 0);
      }
      {
        const int dd = chunk >> 3, c8 = chunk & 7;
        const uint16_t* g = Vtbase + (size_t)dd * T_ + kv0 + ((c8 ^ XM(dd)) * 8);
        __builtin_amdgcn_global_load_lds((const __attribute__((address_space(1))) unsigned int*)g,
                                         (__attribute__((address_space(3))) unsigned int*)(Vtl + (it * 256 + w * 64) * 8),
                                         16, 0, 0);
      }
    }
    __syncthreads();

    // S = Q K^T : 4 col-frags x 4 k-frags
    f32x4 s[4];
#pragma unroll
    for (int nf = 0; nf < 4; ++nf) s[nf] = z4;
#pragma unroll
    for (int nf = 0; nf < 4; ++nf)
#pragma unroll
      for (int kk = 0; kk < 4; ++kk) {
        const int row = nf * 16 + lm;
        const short8 kf = *reinterpret_cast<const short8*>(Kl + row * D_ + (((kk * 4 + lg) ^ XM(row)) * 8));
        s[nf] = __builtin_amdgcn_mfma_f32_16x16x32_bf16(qf[kk], kf, s[nf], 0, 0, 0);
      }

    // causal mask (only on the diagonal-intersecting tiles)
    if (kv0 + KVBLK - 1 > wrow0) {
#pragma unroll
      for (int nf = 0; nf < 4; ++nf) {
        const int colg = kv0 + nf * 16 + lm;
#pragma unroll
        for (int r = 0; r < 4; ++r) {
          const int rowg = wrow0 + lg * 4 + r;
          if (colg > rowg) s[nf][r] = -1e30f;
        }
      }
    }

    // per-lane raw tile max; only reduce across lanes if defer threshold trips
    float tmax[4];
#pragma unroll
    for (int r = 0; r < 4; ++r)
      tmax[r] = fmaxf(fmaxf(s[0][r], s[1][r]), fmaxf(s[2][r], s[3][r]));
    bool grow = false;
#pragma unroll
    for (int r = 0; r < 4; ++r) grow = grow || (tmax[r] > mrow[r] + 8.f);
    if (__any((int)grow)) {
#pragma unroll
      for (int r = 0; r < 4; ++r) {
        float v = tmax[r];
        v = fmaxf(v, __shfl_xor(v, 1));
        v = fmaxf(v, __shfl_xor(v, 2));
        v = fmaxf(v, __shfl_xor(v, 4));
        v = fmaxf(v, __shfl_xor(v, 8));
        const float nm = fmaxf(mrow[r], v);
        const float al = exp2f(mrow[r] - nm);
        mrow[r] = nm;
        osum[r] *= al;
#pragma unroll
        for (int f = 0; f < 8; ++f) o[f][r] *= al;
      }
    }
    // P = exp2(S - m), write to wave-private LDS (C/D layout -> A-frag layout)
#pragma unroll
    for (int nf = 0; nf < 4; ++nf)
#pragma unroll
      for (int r = 0; r < 4; ++r) {
        const float p = exp2f(s[nf][r] - mrow[r]);
        const int prow = lg * 4 + r;
        const int pchunk = (nf * 2 + (lm >> 3)) ^ XM(prow);
        Pw[prow * 64 + pchunk * 8 + (lm & 7)] = hwbf(p);
      }
    // P is wave-private: drain ds_writes; no cross-wave barrier needed
    asm volatile("s_waitcnt lgkmcnt(0)" ::: "memory");
    short8 pf[2];
#pragma unroll
    for (int ks = 0; ks < 2; ++ks)
      pf[ks] = *reinterpret_cast<const short8*>(Pw + lm * 64 + (((ks * 4 + lg) ^ XM(lm)) * 8));
    // PV + ones-column row-sum
#pragma unroll
    for (int ks = 0; ks < 2; ++ks)
      osum = __builtin_amdgcn_mfma_f32_16x16x32_bf16(pf[ks], vone, osum, 0, 0, 0);
#pragma unroll
    for (int f = 0; f < 8; ++f)
#pragma unroll
      for (int ks = 0; ks < 2; ++ks) {
        const int dd = f * 16 + lm;
        const short8 vf = *reinterpret_cast<const short8*>(Vtl + dd * KVBLK + (((ks * 4 + lg) ^ XM(dd)) * 8));
        o[f] = __builtin_amdgcn_mfma_f32_16x16x32_bf16(pf[ks], vf, o[f], 0, 0, 0);
      }
  }

  float rcp[4];
#pragma unroll
  for (int r = 0; r < 4; ++r) rcp[r] = 1.0f / osum[r];
#pragma unroll
  for (int f = 0; f < 8; ++f) {
    const int col = h * D_ + f * 16 + lm;
#pragma unroll
    for (int r = 0; r < 4; ++r) {
      const int trow = wrow0 + lg * 4 + r;
      Ab[((size_t)(b * T_ + trow)) * (H_ * D_) + col] = f2bf(o[f][r] * rcp[r]);
    }
  }
}

// ---------------- launch ----------------
extern "C" void kernel_launch(void* const* d_in, const int* in_sizes, int n_in,
                              void* d_out, int out_size, void* d_ws, size_t ws_size,
                              hipStream_t stream) {
  const float* hidden = (const float*)d_in[0];
  const float* cosp   = (const float*)d_in[1];
  const float* sinp   = (const float*)d_in[2];
  // d_in[3] = attention_mask: exactly causal, implemented in-kernel
  const float* Wq = (const float*)d_in[4];
  const float* bq = (const float*)d_in[5];
  const float* Wk = (const float*)d_in[6];
  const float* bk = (const float*)d_in[7];
  const float* Wv = (const float*)d_in[8];
  const float* bv = (const float*)d_in[9];
  const float* Wo = (const float*)d_in[10];

  char* ws = (char*)d_ws;
  uint16_t* hidb   = (uint16_t*)(ws);              // 4096x2048 bf16   16,777,216 B
  uint16_t* wqkv   = (uint16_t*)(ws + 16777216);   // 3072x2048 bf16   12,582,912 B
  uint16_t* wob    = (uint16_t*)(ws + 29360128);   // 2048x2048 bf16    8,388,608 B
  float*    biasq  = (float*)   (ws + 37748736);   // 3072 f32             12,288 B
  uint16_t* qkvraw = (uint16_t*)(ws + 37761024);   // 4096x3072 bf16   25,165,824 B
  uint16_t* Qb     = (uint16_t*)(ws + 62926848);   // [2][16][2048][128] 16,777,216 B
  uint16_t* Kb     = (uint16_t*)(ws + 79704064);   // [2][4][2048][128]   4,194,304 B
  uint16_t* VtG    = (uint16_t*)(ws + 83898368);   // [2][4][128][2048]   4,194,304 B
  uint16_t* Ab     = (uint16_t*)(ws + 88092672);   // [2][2048][2048]   16,777,216 B

  cvt_f32_bf16<<<8192, 256, 0, stream>>>(hidden, hidb, 8388608);
  cvt_f32_bf16<<<4096, 256, 0, stream>>>(Wq, wqkv, 4194304);
  cvt_f32_bf16<<<1024, 256, 0, stream>>>(Wk, wqkv + 4194304, 1048576);
  cvt_f32_bf16<<<1024, 256, 0, stream>>>(Wv, wqkv + 5242880, 1048576);
  cvt_f32_bf16<<<4096, 256, 0, stream>>>(Wo, wob, 4194304);
  concat_bias<<<12, 256, 0, stream>>>(bq, bk, bv, biasq);

  // QKV projection: [4096,2048] x [3072,2048]^T -> [4096,3072] (+bias)
  gemm_bt<false, true><<<dim3(24, 32), 256, 0, stream>>>(hidb, wqkv, qkvraw, biasq, 4096, 3072, 2048);
  // RoPE + scatter Q,K (Q pre-scaled by 1/sqrt(D)*log2e)
  rope_scatter<<<4096, 320, 0, stream>>>(qkvraw, cosp, sinp, Qb, Kb);
  // V transpose to [d][t]
  transpose_v<<<dim3(128, 8), 256, 0, stream>>>(qkvraw, VtG);
  // causal GQA flash attention -> Ab [b][t][h*128+d] bf16
  attn_fwd<<<dim3(32, 32), 256, 0, stream>>>(Qb, Kb, VtG, Ab);
  // output projection: [4096,2048] x [2048,2048]^T -> d_out fp32
  gemm_bt<true, false><<<dim3(16, 32), 256, 0, stream>>>(Ab, wob, d_out, nullptr, 4096, 2048, 2048);
}

// Round 11
// 241.085 us; speedup vs baseline: 1.7295x; 1.1159x over previous
//
#include <hip/hip_runtime.h>
#include <hip/hip_bf16.h>
#include <stdint.h>

#define B_ 2
#define T_ 2048
#define HID_ 2048
#define H_ 16
#define KVH_ 4
#define D_ 128

typedef __attribute__((ext_vector_type(8))) short short8;
typedef __attribute__((ext_vector_type(4))) float f32x4;

__device__ __forceinline__ uint16_t f2bf(float x) {
  union { float f; uint32_t u; } c; c.f = x;
  uint32_t r = c.u + 0x7fffu + ((c.u >> 16) & 1u);
  return (uint16_t)(r >> 16);
}
__device__ __forceinline__ float bf2f(uint16_t b) {
  union { uint32_t u; float f; } c; c.u = ((uint32_t)b) << 16;
  return c.f;
}
__device__ __forceinline__ uint16_t hwbf(float x) {
  __hip_bfloat16 h = __float2bfloat16(x);
  return *reinterpret_cast<uint16_t*>(&h);
}

// chunk-XOR swizzle for LDS tiles (16B granules), de-aliases r and r+8
#define XM(r) (((r) & 7) ^ (((r) >> 1) & 4))

// ---------------- fp32 -> bf16 convert ----------------
__global__ __launch_bounds__(256) void cvt_f32_bf16(const float* __restrict__ in,
                                                    uint16_t* __restrict__ out, int n) {
  int i = (blockIdx.x * 256 + threadIdx.x) * 4;
  if (i >= n) return;
  const float4 v = *reinterpret_cast<const float4*>(in + i);
  union { uint16_t s[4]; uint2 u; } pk;
  pk.s[0] = f2bf(v.x); pk.s[1] = f2bf(v.y); pk.s[2] = f2bf(v.z); pk.s[3] = f2bf(v.w);
  *reinterpret_cast<uint2*>(out + i) = pk.u;
}

__global__ __launch_bounds__(256) void concat_bias(const float* __restrict__ bq,
                                                   const float* __restrict__ bk,
                                                   const float* __restrict__ bv,
                                                   float* __restrict__ out) {
  int i = blockIdx.x * 256 + threadIdx.x;
  if (i < 2048) out[i] = bq[i];
  else if (i < 2560) out[i] = bk[i - 2048];
  else if (i < 3072) out[i] = bv[i - 2560];
}

// ---------------- bt-GEMM: A[M][K] bf16, Bt[N][K] bf16 -> C[M][N] ----------------
// 128x128 tile, BK=64, 4 waves. 2-phase prefetch double-buffer: stage(t+1)
// issued BEFORE compute(t); single __syncthreads per K-step (implicit
// vmcnt0+lgkm0 drain makes the buffer swap race-free). LDS staged via
// global_load_lds with XOR-pre-swizzled global source; fragment reads apply
// the same XOR -> 2-way (free) bank access. XCD-bijective block swizzle.
#define BM 128
#define BN 128
#define BK 64

template<bool OUT_F32, bool HAS_BIAS>
__global__ __launch_bounds__(256, 2) void gemm_bt(const uint16_t* __restrict__ A,
                                                  const uint16_t* __restrict__ Bt,
                                                  void* __restrict__ Cv,
                                                  const float* __restrict__ bias,
                                                  int M, int N, int K) {
  __shared__ __align__(16) uint16_t Al[2][BM * BK];   // 2 x 16 KB
  __shared__ __align__(16) uint16_t Bl[2][BN * BK];   // 2 x 16 KB  (total 64 KB)
  const int tid = threadIdx.x;
  const int w = tid >> 6;
  const int lane = tid & 63;
  const int wr = w >> 1, wc = w & 1;
  const int lm = lane & 15, lg = lane >> 4;

  // XCD-bijective block swizzle (nwg % 8 == 0 for all shapes used here)
  const int GX = gridDim.x;
  const int nwg = GX * gridDim.y;
  int bid = blockIdx.y * GX + blockIdx.x;
  bid = (bid & 7) * (nwg >> 3) + (bid >> 3);
  const int bm = (bid / GX) * BM;
  const int bn = (bid % GX) * BN;

  f32x4 acc[4][4];
  const f32x4 z4 = {0.f, 0.f, 0.f, 0.f};
#pragma unroll
  for (int i = 0; i < 4; ++i)
#pragma unroll
    for (int j = 0; j < 4; ++j) acc[i][j] = z4;

  const int nt = K >> 6;  // K / BK

  // stage K-tile t into buffer b (A rows bm.., Bt rows bn.., cols t*BK..)
  auto stage = [&](int b, int t) {
    const int k0 = t * BK;
#pragma unroll
    for (int it = 0; it < 4; ++it) {
      const int chunk = it * 256 + tid;          // 0..1023 (row r, 16B chunk c8)
      const int r = chunk >> 3, c8 = chunk & 7;
      const int csw = (c8 ^ XM(r)) * 8;
      const uint16_t* gA = A + (size_t)(bm + r) * K + k0 + csw;
      const uint16_t* gB = Bt + (size_t)(bn + r) * K + k0 + csw;
      __builtin_amdgcn_global_load_lds((const __attribute__((address_space(1))) unsigned int*)gA,
                                       (__attribute__((address_space(3))) unsigned int*)(&Al[b][0] + chunk * 8),
                                       16, 0, 0);
      __builtin_amdgcn_global_load_lds((const __attribute__((address_space(1))) unsigned int*)gB,
                                       (__attribute__((address_space(3))) unsigned int*)(&Bl[b][0] + chunk * 8),
                                       16, 0, 0);
    }
  };

  // prologue: stage tile 0
  stage(0, 0);
  __syncthreads();

  int cur = 0;
  for (int t = 0; t < nt; ++t) {
    if (t + 1 < nt) stage(cur ^ 1, t + 1);   // prefetch next tile (in flight during compute)
#pragma unroll
    for (int kk = 0; kk < 2; ++kk) {
      short8 af[4], bfr[4];
#pragma unroll
      for (int mi = 0; mi < 4; ++mi) {
        const int r = wr * 64 + mi * 16 + lm;
        af[mi] = *reinterpret_cast<const short8*>(&Al[cur][r * BK + (((kk * 4 + lg) ^ XM(r)) * 8)]);
      }
#pragma unroll
      for (int ni = 0; ni < 4; ++ni) {
        const int r = wc * 64 + ni * 16 + lm;
        bfr[ni] = *reinterpret_cast<const short8*>(&Bl[cur][r * BK + (((kk * 4 + lg) ^ XM(r)) * 8)]);
      }
#pragma unroll
      for (int mi = 0; mi < 4; ++mi)
#pragma unroll
        for (int ni = 0; ni < 4; ++ni)
          acc[mi][ni] = __builtin_amdgcn_mfma_f32_16x16x32_bf16(af[mi], bfr[ni], acc[mi][ni], 0, 0, 0);
    }
    __syncthreads();  // drains prefetch (vmcnt) + LDS reads; buffer swap safe
    cur ^= 1;
  }

#pragma unroll
  for (int mi = 0; mi < 4; ++mi) {
#pragma unroll
    for (int ni = 0; ni < 4; ++ni) {
      const int col = bn + wc * 64 + ni * 16 + lm;
      float bb = 0.f;
      if (HAS_BIAS) bb = bias[col];
#pragma unroll
      for (int r = 0; r < 4; ++r) {
        const int row = bm + wr * 64 + mi * 16 + lg * 4 + r;
        const float v = acc[mi][ni][r] + bb;
        if (OUT_F32) reinterpret_cast<float*>(Cv)[(size_t)row * N + col] = v;
        else reinterpret_cast<uint16_t*>(Cv)[(size_t)row * N + col] = f2bf(v);
      }
    }
  }
}

// ---------------- RoPE + scatter, vectorized (Q scaled by 1/sqrt(D)*log2e) ----------------
#define SC_Q 0.1275523865396698f  // 0.08838834764831845 * 1.44269504088896341

__global__ __launch_bounds__(320) void rope_scatter(const uint16_t* __restrict__ raw,
                                                    const float* __restrict__ cosp,
                                                    const float* __restrict__ sinp,
                                                    uint16_t* __restrict__ Qo,
                                                    uint16_t* __restrict__ Ko) {
  const int c8 = threadIdx.x;            // 0..319 (chunk of 8 elems)
  const int m = blockIdx.x;              // 0..4095
  const int b = m >> 11, tt = m & 2047;
  const int c = c8 * 8;                  // 0..2552
  const int d = c & 127;
  const size_t rowoff = (size_t)m * 3072;
  union { short8 v; uint16_t s[8]; } x8, p8, o8;
  x8.v = *reinterpret_cast<const short8*>(raw + rowoff + c);
  p8.v = *reinterpret_cast<const short8*>(raw + rowoff + (c ^ 64));
  const float* cb = cosp + ((size_t)b * T_ + tt) * D_ + d;
  const float* sb = sinp + ((size_t)b * T_ + tt) * D_ + d;
  const bool isq = (c < 2048);
  const float scale = isq ? SC_Q : 1.0f;
  const float sgn = (d < 64) ? -1.f : 1.f;
#pragma unroll
  for (int j = 0; j < 8; ++j) {
    const float x = bf2f(x8.s[j]);
    const float px = bf2f(p8.s[j]);
    o8.s[j] = f2bf((x * cb[j] + sgn * px * sb[j]) * scale);
  }
  if (isq) {
    const int hh = c >> 7;
    *reinterpret_cast<short8*>(Qo + (((size_t)(b * H_ + hh)) * T_ + tt) * D_ + d) = o8.v;
  } else {
    const int hh = (c - 2048) >> 7;
    *reinterpret_cast<short8*>(Ko + (((size_t)(b * KVH_ + hh)) * T_ + tt) * D_ + d) = o8.v;
  }
}

// ---------------- V transpose: qkvraw cols 2560..3071 -> VtG[b][kvh][d][t] ----------------
__global__ __launch_bounds__(256) void transpose_v(const uint16_t* __restrict__ raw,
                                                   uint16_t* __restrict__ VtG) {
  const int hb = blockIdx.y;            // b*4+kvh, 0..7
  const int b = hb >> 2, kvh = hb & 3;
  const int d = threadIdx.x & 127;
  const int tw = threadIdx.x >> 7;      // 0..1
  const int t0 = blockIdx.x * 16 + tw * 8;
  const uint16_t* src = raw + ((size_t)(b * T_ + t0)) * 3072 + 2560 + kvh * 128 + d;
  union { uint16_t s[8]; short8 v; } pk;
#pragma unroll
  for (int j = 0; j < 8; ++j) pk.s[j] = src[(size_t)j * 3072];
  *reinterpret_cast<short8*>(VtG + ((size_t)hb * D_ + d) * T_ + t0) = pk.v;
}

// ---------------- causal GQA flash attention ----------------
// QBLK=64 (16 q-rows/wave), KVBLK=64, 1024 blocks all-resident at 4 blk/CU.
// LDS linear + chunk-XOR swizzle XM(row); staging swizzles the GLOBAL source
// chunk (gload_lds dest linear), reads/P-writes swizzle the LDS chunk index.
// Row-sum denominator via ones-column MFMA (no rsum shuffle); tmax shuffle
// reduce only when the defer-max threshold trips (rare after tile 0).
#define KVBLK 64

__global__ __launch_bounds__(256, 4) void attn_fwd(const uint16_t* __restrict__ Qb,
                                                   const uint16_t* __restrict__ Kb,
                                                   const uint16_t* __restrict__ VtG,
                                                   uint16_t* __restrict__ Ab) {
  __shared__ __align__(16) uint16_t Kl[KVBLK * D_];     // 16384 B
  __shared__ __align__(16) uint16_t Vtl[D_ * KVBLK];    // 16384 B
  __shared__ __align__(16) uint16_t Pl[4 * 16 * 64];    //  8192 B  (total 40960 -> 4 blk/CU)
  const int tid = threadIdx.x;
  const int w = tid >> 6, lane = tid & 63;
  const int lm = lane & 15, lg = lane >> 4;
  const int bh = blockIdx.y;
  const int b = bh >> 4, h = bh & 15;
  const int kvh = h >> 2;
  const int qt = (blockIdx.x + bh) & 31;  // load-balance swizzle, 32 q-tiles of 64
  const int q0 = qt * 64;
  const int wrow0 = q0 + w * 16;          // this wave's first q-row

  // Q fragments (A-frag: m=lane&15, k=(lane>>4)*8+j); Q pre-scaled by SC_Q
  const uint16_t* Qw = Qb + (((size_t)(b * H_ + h)) * T_ + wrow0) * D_;
  short8 qf[4];
#pragma unroll
  for (int kk = 0; kk < 4; ++kk)
    qf[kk] = *reinterpret_cast<const short8*>(Qw + (size_t)lm * D_ + kk * 32 + lg * 8);

  f32x4 o[8];
  const f32x4 z4 = {0.f, 0.f, 0.f, 0.f};
#pragma unroll
  for (int f = 0; f < 8; ++f) o[f] = z4;
  f32x4 osum = z4;                         // row-sum accumulator (ones-column MFMA)
  float mrow[4] = {-1e30f, -1e30f, -1e30f, -1e30f};
  short8 vone;
#pragma unroll
  for (int j = 0; j < 8; ++j) vone[j] = (short)0x3F80;  // bf16 1.0

  const uint16_t* Kbase = Kb + ((size_t)(b * KVH_ + kvh)) * T_ * D_;
  const uint16_t* Vtbase = VtG + ((size_t)(b * KVH_ + kvh)) * D_ * T_;
  uint16_t* Pw = Pl + w * 16 * 64;

  const int nkv = qt + 1;   // exact causal KV range for this q-tile
  for (int t = 0; t < nkv; ++t) {
    const int kv0 = t * KVBLK;
    __syncthreads();  // prior tile's LDS reads done before restage
    // stage K [64 rows][16 chunks] and Vt [128 rows][8 chunks] via global_load_lds;
    // LDS dest linear in chunk id, global source column-chunk XOR-swizzled.
#pragma unroll
    for (int it = 0; it < 4; ++it) {
      const int chunk = it * 256 + tid;
      {
        const int r = chunk >> 4, c16 = chunk & 15;
        const uint16_t* g = Kbase + (size_t)(kv0 + r) * D_ + ((c16 ^ XM(r)) * 8);
        __builtin_amdgcn_global_load_lds((const __attribute__((address_space(1))) unsigned int*)g,
                                         (__attribute__((address_space(3))) unsigned int*)(Kl + (it * 256 + w * 64) * 8),
                                         16, 0, 0);
      }
      {
        const int dd = chunk >> 3, c8 = chunk & 7;
        const uint16_t* g = Vtbase + (size_t)dd * T_ + kv0 + ((c8 ^ XM(dd)) * 8);
        __builtin_amdgcn_global_load_lds((const __attribute__((address_space(1))) unsigned int*)g,
                                         (__attribute__((address_space(3))) unsigned int*)(Vtl + (it * 256 + w * 64) * 8),
                                         16, 0, 0);
      }
    }
    __syncthreads();

    // S = Q K^T : 4 col-frags x 4 k-frags
    f32x4 s[4];
#pragma unroll
    for (int nf = 0; nf < 4; ++nf) s[nf] = z4;
#pragma unroll
    for (int nf = 0; nf < 4; ++nf)
#pragma unroll
      for (int kk = 0; kk < 4; ++kk) {
        const int row = nf * 16 + lm;
        const short8 kf = *reinterpret_cast<const short8*>(Kl + row * D_ + (((kk * 4 + lg) ^ XM(row)) * 8));
        s[nf] = __builtin_amdgcn_mfma_f32_16x16x32_bf16(qf[kk], kf, s[nf], 0, 0, 0);
      }

    // causal mask (only on the diagonal-intersecting tiles)
    if (kv0 + KVBLK - 1 > wrow0) {
#pragma unroll
      for (int nf = 0; nf < 4; ++nf) {
        const int colg = kv0 + nf * 16 + lm;
#pragma unroll
        for (int r = 0; r < 4; ++r) {
          const int rowg = wrow0 + lg * 4 + r;
          if (colg > rowg) s[nf][r] = -1e30f;
        }
      }
    }

    // per-lane raw tile max; only reduce across lanes if defer threshold trips
    float tmax[4];
#pragma unroll
    for (int r = 0; r < 4; ++r)
      tmax[r] = fmaxf(fmaxf(s[0][r], s[1][r]), fmaxf(s[2][r], s[3][r]));
    bool grow = false;
#pragma unroll
    for (int r = 0; r < 4; ++r) grow = grow || (tmax[r] > mrow[r] + 8.f);
    if (__any((int)grow)) {
#pragma unroll
      for (int r = 0; r < 4; ++r) {
        float v = tmax[r];
        v = fmaxf(v, __shfl_xor(v, 1));
        v = fmaxf(v, __shfl_xor(v, 2));
        v = fmaxf(v, __shfl_xor(v, 4));
        v = fmaxf(v, __shfl_xor(v, 8));
        const float nm = fmaxf(mrow[r], v);
        const float al = exp2f(mrow[r] - nm);
        mrow[r] = nm;
        osum[r] *= al;
#pragma unroll
        for (int f = 0; f < 8; ++f) o[f][r] *= al;
      }
    }
    // P = exp2(S - m), write to wave-private LDS (C/D layout -> A-frag layout)
#pragma unroll
    for (int nf = 0; nf < 4; ++nf)
#pragma unroll
      for (int r = 0; r < 4; ++r) {
        const float p = exp2f(s[nf][r] - mrow[r]);
        const int prow = lg * 4 + r;
        const int pchunk = (nf * 2 + (lm >> 3)) ^ XM(prow);
        Pw[prow * 64 + pchunk * 8 + (lm & 7)] = hwbf(p);
      }
    // P is wave-private: drain ds_writes; no cross-wave barrier needed
    asm volatile("s_waitcnt lgkmcnt(0)" ::: "memory");
    short8 pf[2];
#pragma unroll
    for (int ks = 0; ks < 2; ++ks)
      pf[ks] = *reinterpret_cast<const short8*>(Pw + lm * 64 + (((ks * 4 + lg) ^ XM(lm)) * 8));
    // PV + ones-column row-sum
#pragma unroll
    for (int ks = 0; ks < 2; ++ks)
      osum = __builtin_amdgcn_mfma_f32_16x16x32_bf16(pf[ks], vone, osum, 0, 0, 0);
#pragma unroll
    for (int f = 0; f < 8; ++f)
#pragma unroll
      for (int ks = 0; ks < 2; ++ks) {
        const int dd = f * 16 + lm;
        const short8 vf = *reinterpret_cast<const short8*>(Vtl + dd * KVBLK + (((ks * 4 + lg) ^ XM(dd)) * 8));
        o[f] = __builtin_amdgcn_mfma_f32_16x16x32_bf16(pf[ks], vf, o[f], 0, 0, 0);
      }
  }

  float rcp[4];
#pragma unroll
  for (int r = 0; r < 4; ++r) rcp[r] = 1.0f / osum[r];
#pragma unroll
  for (int f = 0; f < 8; ++f) {
    const int col = h * D_ + f * 16 + lm;
#pragma unroll
    for (int r = 0; r < 4; ++r) {
      const int trow = wrow0 + lg * 4 + r;
      Ab[((size_t)(b * T_ + trow)) * (H_ * D_) + col] = f2bf(o[f][r] * rcp[r]);
    }
  }
}

// ---------------- launch ----------------
extern "C" void kernel_launch(void* const* d_in, const int* in_sizes, int n_in,
                              void* d_out, int out_size, void* d_ws, size_t ws_size,
                              hipStream_t stream) {
  const float* hidden = (const float*)d_in[0];
  const float* cosp   = (const float*)d_in[1];
  const float* sinp   = (const float*)d_in[2];
  // d_in[3] = attention_mask: exactly causal, implemented in-kernel
  const float* Wq = (const float*)d_in[4];
  const float* bq = (const float*)d_in[5];
  const float* Wk = (const float*)d_in[6];
  const float* bk = (const float*)d_in[7];
  const float* Wv = (const float*)d_in[8];
  const float* bv = (const float*)d_in[9];
  const float* Wo = (const float*)d_in[10];

  char* ws = (char*)d_ws;
  uint16_t* hidb   = (uint16_t*)(ws);              // 4096x2048 bf16   16,777,216 B
  uint16_t* wqkv   = (uint16_t*)(ws + 16777216);   // 3072x2048 bf16   12,582,912 B
  uint16_t* wob    = (uint16_t*)(ws + 29360128);   // 2048x2048 bf16    8,388,608 B
  float*    biasq  = (float*)   (ws + 37748736);   // 3072 f32             12,288 B
  uint16_t* qkvraw = (uint16_t*)(ws + 37761024);   // 4096x3072 bf16   25,165,824 B
  uint16_t* Qb     = (uint16_t*)(ws + 62926848);   // [2][16][2048][128] 16,777,216 B
  uint16_t* Kb     = (uint16_t*)(ws + 79704064);   // [2][4][2048][128]   4,194,304 B
  uint16_t* VtG    = (uint16_t*)(ws + 83898368);   // [2][4][128][2048]   4,194,304 B
  uint16_t* Ab     = (uint16_t*)(ws + 88092672);   // [2][2048][2048]   16,777,216 B

  cvt_f32_bf16<<<8192, 256, 0, stream>>>(hidden, hidb, 8388608);
  cvt_f32_bf16<<<4096, 256, 0, stream>>>(Wq, wqkv, 4194304);
  cvt_f32_bf16<<<1024, 256, 0, stream>>>(Wk, wqkv + 4194304, 1048576);
  cvt_f32_bf16<<<1024, 256, 0, stream>>>(Wv, wqkv + 5242880, 1048576);
  cvt_f32_bf16<<<4096, 256, 0, stream>>>(Wo, wob, 4194304);
  concat_bias<<<12, 256, 0, stream>>>(bq, bk, bv, biasq);

  // QKV projection: [4096,2048] x [3072,2048]^T -> [4096,3072] (+bias)
  gemm_bt<false, true><<<dim3(24, 32), 256, 0, stream>>>(hidb, wqkv, qkvraw, biasq, 4096, 3072, 2048);
  // RoPE + scatter Q,K (Q pre-scaled by 1/sqrt(D)*log2e)
  rope_scatter<<<4096, 320, 0, stream>>>(qkvraw, cosp, sinp, Qb, Kb);
  // V transpose to [d][t]
  transpose_v<<<dim3(128, 8), 256, 0, stream>>>(qkvraw, VtG);
  // causal GQA flash attention -> Ab [b][t][h*128+d] bf16
  attn_fwd<<<dim3(32, 32), 256, 0, stream>>>(Qb, Kb, VtG, Ab);
  // output projection: [4096,2048] x [2048,2048]^T -> d_out fp32
  gemm_bt<true, false><<<dim3(16, 32), 256, 0, stream>>>(Ab, wob, d_out, nullptr, 4096, 2048, 2048);
}

// Round 12
// 228.000 us; speedup vs baseline: 1.8288x; 1.0574x over previous
//
#include <hip/hip_runtime.h>
#include <hip/hip_bf16.h>
#include <stdint.h>

#define B_ 2
#define T_ 2048
#define HID_ 2048
#define H_ 16
#define KVH_ 4
#define D_ 128

typedef __attribute__((ext_vector_type(8))) short short8;
typedef __attribute__((ext_vector_type(4))) float f32x4;

__device__ __forceinline__ uint16_t f2bf(float x) {
  union { float f; uint32_t u; } c; c.f = x;
  uint32_t r = c.u + 0x7fffu + ((c.u >> 16) & 1u);
  return (uint16_t)(r >> 16);
}
__device__ __forceinline__ float bf2f(uint16_t b) {
  union { uint32_t u; float f; } c; c.u = ((uint32_t)b) << 16;
  return c.f;
}
__device__ __forceinline__ uint16_t hwbf(float x) {
  __hip_bfloat16 h = __float2bfloat16(x);
  return *reinterpret_cast<uint16_t*>(&h);
}

// chunk-XOR swizzle for LDS tiles (16B granules), de-aliases r and r+8
#define XM(r) (((r) & 7) ^ (((r) >> 1) & 4))

// ---------------- fp32 -> bf16 convert ----------------
__global__ __launch_bounds__(256) void cvt_f32_bf16(const float* __restrict__ in,
                                                    uint16_t* __restrict__ out, int n) {
  int i = (blockIdx.x * 256 + threadIdx.x) * 4;
  if (i >= n) return;
  const float4 v = *reinterpret_cast<const float4*>(in + i);
  union { uint16_t s[4]; uint2 u; } pk;
  pk.s[0] = f2bf(v.x); pk.s[1] = f2bf(v.y); pk.s[2] = f2bf(v.z); pk.s[3] = f2bf(v.w);
  *reinterpret_cast<uint2*>(out + i) = pk.u;
}

__global__ __launch_bounds__(256) void concat_bias(const float* __restrict__ bq,
                                                   const float* __restrict__ bk,
                                                   const float* __restrict__ bv,
                                                   float* __restrict__ out) {
  int i = blockIdx.x * 256 + threadIdx.x;
  if (i < 2048) out[i] = bq[i];
  else if (i < 2560) out[i] = bk[i - 2048];
  else if (i < 3072) out[i] = bv[i - 2560];
}

// ---------------- bt-GEMM: A[M][K] bf16, Bt[N][K] bf16 -> C[M][N] ----------------
#define BM 128
#define BN 128
#define BK 64

template<bool OUT_F32, bool HAS_BIAS>
__global__ __launch_bounds__(256, 2) void gemm_bt(const uint16_t* __restrict__ A,
                                                  const uint16_t* __restrict__ Bt,
                                                  void* __restrict__ Cv,
                                                  const float* __restrict__ bias,
                                                  int M, int N, int K) {
  __shared__ __align__(16) uint16_t Al[2][BM * BK];   // 2 x 16 KB
  __shared__ __align__(16) uint16_t Bl[2][BN * BK];   // 2 x 16 KB  (total 64 KB)
  const int tid = threadIdx.x;
  const int w = tid >> 6;
  const int lane = tid & 63;
  const int wr = w >> 1, wc = w & 1;
  const int lm = lane & 15, lg = lane >> 4;

  // XCD-bijective block swizzle (nwg % 8 == 0 for all shapes used here)
  const int GX = gridDim.x;
  const int nwg = GX * gridDim.y;
  int bid = blockIdx.y * GX + blockIdx.x;
  bid = (bid & 7) * (nwg >> 3) + (bid >> 3);
  const int bm = (bid / GX) * BM;
  const int bn = (bid % GX) * BN;

  f32x4 acc[4][4];
  const f32x4 z4 = {0.f, 0.f, 0.f, 0.f};
#pragma unroll
  for (int i = 0; i < 4; ++i)
#pragma unroll
    for (int j = 0; j < 4; ++j) acc[i][j] = z4;

  const int nt = K >> 6;  // K / BK

  auto stage = [&](int b, int t) {
    const int k0 = t * BK;
#pragma unroll
    for (int it = 0; it < 4; ++it) {
      const int chunk = it * 256 + tid;          // 0..1023 (row r, 16B chunk c8)
      const int r = chunk >> 3, c8 = chunk & 7;
      const int csw = (c8 ^ XM(r)) * 8;
      const uint16_t* gA = A + (size_t)(bm + r) * K + k0 + csw;
      const uint16_t* gB = Bt + (size_t)(bn + r) * K + k0 + csw;
      __builtin_amdgcn_global_load_lds((const __attribute__((address_space(1))) unsigned int*)gA,
                                       (__attribute__((address_space(3))) unsigned int*)(&Al[b][0] + chunk * 8),
                                       16, 0, 0);
      __builtin_amdgcn_global_load_lds((const __attribute__((address_space(1))) unsigned int*)gB,
                                       (__attribute__((address_space(3))) unsigned int*)(&Bl[b][0] + chunk * 8),
                                       16, 0, 0);
    }
  };

  stage(0, 0);
  __syncthreads();

  int cur = 0;
  for (int t = 0; t < nt; ++t) {
    if (t + 1 < nt) stage(cur ^ 1, t + 1);   // prefetch next tile
#pragma unroll
    for (int kk = 0; kk < 2; ++kk) {
      short8 af[4], bfr[4];
#pragma unroll
      for (int mi = 0; mi < 4; ++mi) {
        const int r = wr * 64 + mi * 16 + lm;
        af[mi] = *reinterpret_cast<const short8*>(&Al[cur][r * BK + (((kk * 4 + lg) ^ XM(r)) * 8)]);
      }
#pragma unroll
      for (int ni = 0; ni < 4; ++ni) {
        const int r = wc * 64 + ni * 16 + lm;
        bfr[ni] = *reinterpret_cast<const short8*>(&Bl[cur][r * BK + (((kk * 4 + lg) ^ XM(r)) * 8)]);
      }
#pragma unroll
      for (int mi = 0; mi < 4; ++mi)
#pragma unroll
        for (int ni = 0; ni < 4; ++ni)
          acc[mi][ni] = __builtin_amdgcn_mfma_f32_16x16x32_bf16(af[mi], bfr[ni], acc[mi][ni], 0, 0, 0);
    }
    __syncthreads();  // drains prefetch (vmcnt) + LDS reads; buffer swap safe
    cur ^= 1;
  }

#pragma unroll
  for (int mi = 0; mi < 4; ++mi) {
#pragma unroll
    for (int ni = 0; ni < 4; ++ni) {
      const int col = bn + wc * 64 + ni * 16 + lm;
      float bb = 0.f;
      if (HAS_BIAS) bb = bias[col];
#pragma unroll
      for (int r = 0; r < 4; ++r) {
        const int row = bm + wr * 64 + mi * 16 + lg * 4 + r;
        const float v = acc[mi][ni][r] + bb;
        if (OUT_F32) reinterpret_cast<float*>(Cv)[(size_t)row * N + col] = v;
        else reinterpret_cast<uint16_t*>(Cv)[(size_t)row * N + col] = f2bf(v);
      }
    }
  }
}

// ---------------- RoPE + scatter, vectorized (Q scaled by 1/sqrt(D)*log2e) ----------------
#define SC_Q 0.1275523865396698f  // 0.08838834764831845 * 1.44269504088896341

__global__ __launch_bounds__(320) void rope_scatter(const uint16_t* __restrict__ raw,
                                                    const float* __restrict__ cosp,
                                                    const float* __restrict__ sinp,
                                                    uint16_t* __restrict__ Qo,
                                                    uint16_t* __restrict__ Ko) {
  const int c8 = threadIdx.x;            // 0..319 (chunk of 8 elems)
  const int m = blockIdx.x;              // 0..4095
  const int b = m >> 11, tt = m & 2047;
  const int c = c8 * 8;                  // 0..2552
  const int d = c & 127;
  const size_t rowoff = (size_t)m * 3072;
  union { short8 v; uint16_t s[8]; } x8, p8, o8;
  x8.v = *reinterpret_cast<const short8*>(raw + rowoff + c);
  p8.v = *reinterpret_cast<const short8*>(raw + rowoff + (c ^ 64));
  const float* cb = cosp + ((size_t)b * T_ + tt) * D_ + d;
  const float* sb = sinp + ((size_t)b * T_ + tt) * D_ + d;
  const bool isq = (c < 2048);
  const float scale = isq ? SC_Q : 1.0f;
  const float sgn = (d < 64) ? -1.f : 1.f;
#pragma unroll
  for (int j = 0; j < 8; ++j) {
    const float x = bf2f(x8.s[j]);
    const float px = bf2f(p8.s[j]);
    o8.s[j] = f2bf((x * cb[j] + sgn * px * sb[j]) * scale);
  }
  if (isq) {
    const int hh = c >> 7;
    *reinterpret_cast<short8*>(Qo + (((size_t)(b * H_ + hh)) * T_ + tt) * D_ + d) = o8.v;
  } else {
    const int hh = (c - 2048) >> 7;
    *reinterpret_cast<short8*>(Ko + (((size_t)(b * KVH_ + hh)) * T_ + tt) * D_ + d) = o8.v;
  }
}

// ---------------- V transpose: qkvraw cols 2560..3071 -> VtG[b][kvh][d][t] ----------------
__global__ __launch_bounds__(256) void transpose_v(const uint16_t* __restrict__ raw,
                                                   uint16_t* __restrict__ VtG) {
  const int hb = blockIdx.y;            // b*4+kvh, 0..7
  const int b = hb >> 2, kvh = hb & 3;
  const int d = threadIdx.x & 127;
  const int tw = threadIdx.x >> 7;      // 0..1
  const int t0 = blockIdx.x * 16 + tw * 8;
  const uint16_t* src = raw + ((size_t)(b * T_ + t0)) * 3072 + 2560 + kvh * 128 + d;
  union { uint16_t s[8]; short8 v; } pk;
#pragma unroll
  for (int j = 0; j < 8; ++j) pk.s[j] = src[(size_t)j * 3072];
  *reinterpret_cast<short8*>(VtG + ((size_t)hb * D_ + d) * T_ + t0) = pk.v;
}

// ---------------- causal GQA flash attention ----------------
// Paired q-tiles: block (x,bh) processes qtA=(x+bh)&15 then qtB=31-qtA ->
// exactly 33 KV-tiles per block, 512 uniform blocks, 2/CU all-resident (no tail).
// 2-phase prefetch double-buffer on K/V (same structure as gemm_bt): stage(next)
// issued before compute(cur), one __syncthreads per tile hides staging latency.
// LDS 72KB: K 2x16KB + Vt 2x16KB + P 8KB.
#define KVBLK 64

__global__ __launch_bounds__(256, 2) void attn_fwd(const uint16_t* __restrict__ Qb,
                                                   const uint16_t* __restrict__ Kb,
                                                   const uint16_t* __restrict__ VtG,
                                                   uint16_t* __restrict__ Ab) {
  __shared__ __align__(16) uint16_t Kl[2][KVBLK * D_];   // 32768 B
  __shared__ __align__(16) uint16_t Vtl[2][D_ * KVBLK];  // 32768 B
  __shared__ __align__(16) uint16_t Pl[4 * 16 * 64];     //  8192 B (total 73728)
  const int tid = threadIdx.x;
  const int w = tid >> 6, lane = tid & 63;
  const int lm = lane & 15, lg = lane >> 4;
  const int bh = blockIdx.y;
  const int b = bh >> 4, h = bh & 15;
  const int kvh = h >> 2;
  const int qtA = (blockIdx.x + bh) & 15;  // first q-tile (0..15)
  const int qtB = 31 - qtA;                // second q-tile (16..31)
  const int nA = qtA + 1;
  const int ntot = 33;                     // nA + (qtB+1) == 33 always

  const uint16_t* Kbase = Kb + ((size_t)(b * KVH_ + kvh)) * T_ * D_;
  const uint16_t* Vtbase = VtG + ((size_t)(b * KVH_ + kvh)) * D_ * T_;
  uint16_t* Pw = Pl + w * 16 * 64;
  const f32x4 z4 = {0.f, 0.f, 0.f, 0.f};

  short8 vone;
#pragma unroll
  for (int j = 0; j < 8; ++j) vone[j] = (short)0x3F80;  // bf16 1.0

  f32x4 o[8];
  f32x4 osum;
  float mrow[4];
  short8 qf[4];

  auto loadQ = [&](int qt) {
    const uint16_t* Qw = Qb + (((size_t)(b * H_ + h)) * T_ + qt * 64 + w * 16) * D_;
#pragma unroll
    for (int kk = 0; kk < 4; ++kk)
      qf[kk] = *reinterpret_cast<const short8*>(Qw + (size_t)lm * D_ + kk * 32 + lg * 8);
  };
  auto resetAcc = [&]() {
#pragma unroll
    for (int f = 0; f < 8; ++f) o[f] = z4;
    osum = z4;
#pragma unroll
    for (int r = 0; r < 4; ++r) mrow[r] = -1e30f;
  };
  auto flush = [&](int qt) {
    const int wr0 = qt * 64 + w * 16;
    float rcp[4];
#pragma unroll
    for (int r = 0; r < 4; ++r) rcp[r] = 1.0f / osum[r];
#pragma unroll
    for (int f = 0; f < 8; ++f) {
      const int col = h * D_ + f * 16 + lm;
#pragma unroll
      for (int r = 0; r < 4; ++r) {
        const int trow = wr0 + lg * 4 + r;
        Ab[((size_t)(b * T_ + trow)) * (H_ * D_) + col] = f2bf(o[f][r] * rcp[r]);
      }
    }
  };
  // stage KV tile (kv0) into buffer buf; LDS dest linear, global source XOR-swizzled
  auto stage = [&](int buf, int kv0) {
#pragma unroll
    for (int it = 0; it < 4; ++it) {
      const int chunk = it * 256 + tid;
      {
        const int r = chunk >> 4, c16 = chunk & 15;
        const uint16_t* g = Kbase + (size_t)(kv0 + r) * D_ + ((c16 ^ XM(r)) * 8);
        __builtin_amdgcn_global_load_lds((const __attribute__((address_space(1))) unsigned int*)g,
                                         (__attribute__((address_space(3))) unsigned int*)(&Kl[buf][0] + (it * 256 + w * 64) * 8),
                                         16, 0, 0);
      }
      {
        const int dd = chunk >> 3, c8 = chunk & 7;
        const uint16_t* g = Vtbase + (size_t)dd * T_ + kv0 + ((c8 ^ XM(dd)) * 8);
        __builtin_amdgcn_global_load_lds((const __attribute__((address_space(1))) unsigned int*)g,
                                         (__attribute__((address_space(3))) unsigned int*)(&Vtl[buf][0] + (it * 256 + w * 64) * 8),
                                         16, 0, 0);
      }
    }
  };

  loadQ(qtA);
  resetAcc();
  stage(0, 0);        // tile 0 of phase A
  __syncthreads();

  int cur = 0;
  for (int g = 0; g < ntot; ++g) {
    const bool inA = g < nA;
    const int t = inA ? g : g - nA;
    const int qt = inA ? qtA : qtB;
    const int kv0 = t * KVBLK;
    const int wrow0 = qt * 64 + w * 16;

    // prefetch next tile (crosses the A->B seam naturally: B starts at kv0=0)
    if (g + 1 < ntot) {
      const int gn = g + 1;
      const int kvn = (gn < nA ? gn : gn - nA) * KVBLK;
      stage(cur ^ 1, kvn);
    }

    // S = Q K^T : 4 col-frags x 4 k-frags
    f32x4 s[4];
#pragma unroll
    for (int nf = 0; nf < 4; ++nf) s[nf] = z4;
#pragma unroll
    for (int nf = 0; nf < 4; ++nf)
#pragma unroll
      for (int kk = 0; kk < 4; ++kk) {
        const int row = nf * 16 + lm;
        const short8 kf = *reinterpret_cast<const short8*>(&Kl[cur][row * D_ + (((kk * 4 + lg) ^ XM(row)) * 8)]);
        s[nf] = __builtin_amdgcn_mfma_f32_16x16x32_bf16(qf[kk], kf, s[nf], 0, 0, 0);
      }

    // causal mask (only on the diagonal-intersecting tiles)
    if (kv0 + KVBLK - 1 > wrow0) {
#pragma unroll
      for (int nf = 0; nf < 4; ++nf) {
        const int colg = kv0 + nf * 16 + lm;
#pragma unroll
        for (int r = 0; r < 4; ++r) {
          const int rowg = wrow0 + lg * 4 + r;
          if (colg > rowg) s[nf][r] = -1e30f;
        }
      }
    }

    // per-lane raw tile max; lane-reduce only when defer threshold trips
    float tmax[4];
#pragma unroll
    for (int r = 0; r < 4; ++r)
      tmax[r] = fmaxf(fmaxf(s[0][r], s[1][r]), fmaxf(s[2][r], s[3][r]));
    bool grow = false;
#pragma unroll
    for (int r = 0; r < 4; ++r) grow = grow || (tmax[r] > mrow[r] + 8.f);
    if (__any((int)grow)) {
#pragma unroll
      for (int r = 0; r < 4; ++r) {
        float v = tmax[r];
        v = fmaxf(v, __shfl_xor(v, 1));
        v = fmaxf(v, __shfl_xor(v, 2));
        v = fmaxf(v, __shfl_xor(v, 4));
        v = fmaxf(v, __shfl_xor(v, 8));
        const float nm = fmaxf(mrow[r], v);
        const float al = exp2f(mrow[r] - nm);
        mrow[r] = nm;
        osum[r] *= al;
#pragma unroll
        for (int f = 0; f < 8; ++f) o[f][r] *= al;
      }
    }
    // P = exp2(S - m) -> wave-private LDS (C/D layout -> A-frag layout)
#pragma unroll
    for (int nf = 0; nf < 4; ++nf)
#pragma unroll
      for (int r = 0; r < 4; ++r) {
        const float p = exp2f(s[nf][r] - mrow[r]);
        const int prow = lg * 4 + r;
        const int pchunk = (nf * 2 + (lm >> 3)) ^ XM(prow);
        Pw[prow * 64 + pchunk * 8 + (lm & 7)] = hwbf(p);
      }
    asm volatile("s_waitcnt lgkmcnt(0)" ::: "memory");
    short8 pf[2];
#pragma unroll
    for (int ks = 0; ks < 2; ++ks)
      pf[ks] = *reinterpret_cast<const short8*>(Pw + lm * 64 + (((ks * 4 + lg) ^ XM(lm)) * 8));
    // PV + ones-column row-sum
#pragma unroll
    for (int ks = 0; ks < 2; ++ks)
      osum = __builtin_amdgcn_mfma_f32_16x16x32_bf16(pf[ks], vone, osum, 0, 0, 0);
#pragma unroll
    for (int f = 0; f < 8; ++f)
#pragma unroll
      for (int ks = 0; ks < 2; ++ks) {
        const int dd = f * 16 + lm;
        const short8 vf = *reinterpret_cast<const short8*>(&Vtl[cur][dd * KVBLK + (((ks * 4 + lg) ^ XM(dd)) * 8)]);
        o[f] = __builtin_amdgcn_mfma_f32_16x16x32_bf16(pf[ks], vf, o[f], 0, 0, 0);
      }

    __syncthreads();  // drains prefetch (vmcnt) + LDS reads; buffer swap safe
    cur ^= 1;

    if (g == nA - 1) {      // seam: finish phase A, start phase B
      flush(qtA);
      loadQ(qtB);
      resetAcc();
    }
  }
  flush(qtB);
}

// ---------------- launch ----------------
extern "C" void kernel_launch(void* const* d_in, const int* in_sizes, int n_in,
                              void* d_out, int out_size, void* d_ws, size_t ws_size,
                              hipStream_t stream) {
  const float* hidden = (const float*)d_in[0];
  const float* cosp   = (const float*)d_in[1];
  const float* sinp   = (const float*)d_in[2];
  // d_in[3] = attention_mask: exactly causal, implemented in-kernel
  const float* Wq = (const float*)d_in[4];
  const float* bq = (const float*)d_in[5];
  const float* Wk = (const float*)d_in[6];
  const float* bk = (const float*)d_in[7];
  const float* Wv = (const float*)d_in[8];
  const float* bv = (const float*)d_in[9];
  const float* Wo = (const float*)d_in[10];

  char* ws = (char*)d_ws;
  uint16_t* hidb   = (uint16_t*)(ws);              // 4096x2048 bf16   16,777,216 B
  uint16_t* wqkv   = (uint16_t*)(ws + 16777216);   // 3072x2048 bf16   12,582,912 B
  uint16_t* wob    = (uint16_t*)(ws + 29360128);   // 2048x2048 bf16    8,388,608 B
  float*    biasq  = (float*)   (ws + 37748736);   // 3072 f32             12,288 B
  uint16_t* qkvraw = (uint16_t*)(ws + 37761024);   // 4096x3072 bf16   25,165,824 B
  uint16_t* Qb     = (uint16_t*)(ws + 62926848);   // [2][16][2048][128] 16,777,216 B
  uint16_t* Kb     = (uint16_t*)(ws + 79704064);   // [2][4][2048][128]   4,194,304 B
  uint16_t* VtG    = (uint16_t*)(ws + 83898368);   // [2][4][128][2048]   4,194,304 B
  uint16_t* Ab     = (uint16_t*)(ws + 88092672);   // [2][2048][2048]   16,777,216 B

  cvt_f32_bf16<<<8192, 256, 0, stream>>>(hidden, hidb, 8388608);
  cvt_f32_bf16<<<4096, 256, 0, stream>>>(Wq, wqkv, 4194304);
  cvt_f32_bf16<<<1024, 256, 0, stream>>>(Wk, wqkv + 4194304, 1048576);
  cvt_f32_bf16<<<1024, 256, 0, stream>>>(Wv, wqkv + 5242880, 1048576);
  cvt_f32_bf16<<<4096, 256, 0, stream>>>(Wo, wob, 4194304);
  concat_bias<<<12, 256, 0, stream>>>(bq, bk, bv, biasq);

  // QKV projection: [4096,2048] x [3072,2048]^T -> [4096,3072] (+bias)
  gemm_bt<false, true><<<dim3(24, 32), 256, 0, stream>>>(hidb, wqkv, qkvraw, biasq, 4096, 3072, 2048);
  // RoPE + scatter Q,K (Q pre-scaled by 1/sqrt(D)*log2e)
  rope_scatter<<<4096, 320, 0, stream>>>(qkvraw, cosp, sinp, Qb, Kb);
  // V transpose to [d][t]
  transpose_v<<<dim3(128, 8), 256, 0, stream>>>(qkvraw, VtG);
  // causal GQA flash attention -> Ab [b][t][h*128+d] bf16 (paired q-tiles)
  attn_fwd<<<dim3(16, 32), 256, 0, stream>>>(Qb, Kb, VtG, Ab);
  // output projection: [4096,2048] x [2048,2048]^T -> d_out fp32
  gemm_bt<true, false><<<dim3(16, 32), 256, 0, stream>>>(Ab, wob, d_out, nullptr, 4096, 2048, 2048);
}

// Round 14
// 211.090 us; speedup vs baseline: 1.9753x; 1.0801x over previous
//
#include <hip/hip_runtime.h>
#include <hip/hip_bf16.h>
#include <stdint.h>

#define B_ 2
#define T_ 2048
#define HID_ 2048
#define H_ 16
#define KVH_ 4
#define D_ 128

typedef __attribute__((ext_vector_type(8))) short short8;
typedef __attribute__((ext_vector_type(4))) float f32x4;

__device__ __forceinline__ uint16_t f2bf(float x) {
  union { float f; uint32_t u; } c; c.f = x;
  uint32_t r = c.u + 0x7fffu + ((c.u >> 16) & 1u);
  return (uint16_t)(r >> 16);
}
__device__ __forceinline__ float bf2f(uint16_t b) {
  union { uint32_t u; float f; } c; c.u = ((uint32_t)b) << 16;
  return c.f;
}
__device__ __forceinline__ uint16_t hwbf(float x) {
  __hip_bfloat16 h = __float2bfloat16(x);
  return *reinterpret_cast<uint16_t*>(&h);
}

// chunk-XOR swizzle for LDS tiles (16B granules), de-aliases r and r+8
#define XM(r) (((r) & 7) ^ (((r) >> 1) & 4))
#define SC_Q 0.1275523865396698f  // 1/sqrt(128) * log2e

// ---------------- merged fp32->bf16 convert + bias concat (one launch) ----------------
__global__ __launch_bounds__(256) void cvt_all(const float* __restrict__ hidden,
                                               const float* __restrict__ Wq,
                                               const float* __restrict__ Wk,
                                               const float* __restrict__ Wv,
                                               const float* __restrict__ Wo,
                                               const float* __restrict__ bq,
                                               const float* __restrict__ bk,
                                               const float* __restrict__ bv,
                                               uint16_t* __restrict__ hidb,
                                               uint16_t* __restrict__ wqkv,
                                               uint16_t* __restrict__ wob,
                                               float* __restrict__ biasq) {
  const int gtid = blockIdx.x * 256 + threadIdx.x;
  const int i = gtid * 4;
  const float* src;
  uint16_t* dst;
  if (i < 8388608)       { src = hidden + i;            dst = hidb + i; }
  else if (i < 12582912) { src = Wq + (i - 8388608);    dst = wqkv + (i - 8388608); }
  else if (i < 13631488) { src = Wk + (i - 12582912);   dst = wqkv + 4194304 + (i - 12582912); }
  else if (i < 14680064) { src = Wv + (i - 13631488);   dst = wqkv + 5242880 + (i - 13631488); }
  else                   { src = Wo + (i - 14680064);   dst = wob + (i - 14680064); }
  const float4 v = *reinterpret_cast<const float4*>(src);
  union { uint16_t s[4]; uint2 u; } pk;
  pk.s[0] = f2bf(v.x); pk.s[1] = f2bf(v.y); pk.s[2] = f2bf(v.z); pk.s[3] = f2bf(v.w);
  *reinterpret_cast<uint2*>(dst) = pk.u;
  if (gtid < 3072)
    biasq[gtid] = (gtid < 2048) ? bq[gtid] : (gtid < 2560) ? bk[gtid - 2048] : bv[gtid - 2560];
}

// ---------------- QKV GEMM with fused bias+RoPE+scatter epilogue ----------------
// A[4096][2048] bf16 x Wqkv[3072][2048]^T. B-frag col remap colb[ni] =
// wc*32+(ni&1)*16+(ni>>1)*64 puts RoPE partner (d^64) = frag ni^2 in the SAME
// thread -> rotation is register-local, no exchange. Epilogue writes directly
// to Qb (bias+RoPE+SC_Q), Kb (bias+RoPE), VtG (bias, transposed 8B-packed).
#define BM 128
#define BN 128
#define BK 64

__global__ __launch_bounds__(256, 2) void gemm_qkv(const uint16_t* __restrict__ A,
                                                   const uint16_t* __restrict__ Bt,
                                                   const float* __restrict__ bias,
                                                   const float* __restrict__ cosp,
                                                   const float* __restrict__ sinp,
                                                   uint16_t* __restrict__ Qo,
                                                   uint16_t* __restrict__ Ko,
                                                   uint16_t* __restrict__ VtG) {
  __shared__ __align__(16) uint16_t Al[2][BM * BK];
  __shared__ __align__(16) uint16_t Bl[2][BN * BK];
  const int K = 2048;
  const int tid = threadIdx.x;
  const int w = tid >> 6;
  const int lane = tid & 63;
  const int wr = w >> 1, wc = w & 1;
  const int lm = lane & 15, lg = lane >> 4;

  const int GX = gridDim.x;
  const int nwg = GX * gridDim.y;
  int bid = blockIdx.y * GX + blockIdx.x;
  bid = (bid & 7) * (nwg >> 3) + (bid >> 3);
  const int bm = (bid / GX) * BM;
  const int bn = (bid % GX) * BN;

  // B-frag col-base per ni: partner (d^64) is ni^2
  const int colb[4] = {wc * 32, wc * 32 + 16, wc * 32 + 64, wc * 32 + 80};

  f32x4 acc[4][4];
  const f32x4 z4 = {0.f, 0.f, 0.f, 0.f};
#pragma unroll
  for (int i = 0; i < 4; ++i)
#pragma unroll
    for (int j = 0; j < 4; ++j) acc[i][j] = z4;

  const int nt = K >> 6;

  auto stage = [&](int b, int t) {
    const int k0 = t * BK;
#pragma unroll
    for (int it = 0; it < 4; ++it) {
      const int chunk = it * 256 + tid;
      const int r = chunk >> 3, c8 = chunk & 7;
      const int csw = (c8 ^ XM(r)) * 8;
      const uint16_t* gA = A + (size_t)(bm + r) * K + k0 + csw;
      const uint16_t* gB = Bt + (size_t)(bn + r) * K + k0 + csw;
      __builtin_amdgcn_global_load_lds((const __attribute__((address_space(1))) unsigned int*)gA,
                                       (__attribute__((address_space(3))) unsigned int*)(&Al[b][0] + chunk * 8),
                                       16, 0, 0);
      __builtin_amdgcn_global_load_lds((const __attribute__((address_space(1))) unsigned int*)gB,
                                       (__attribute__((address_space(3))) unsigned int*)(&Bl[b][0] + chunk * 8),
                                       16, 0, 0);
    }
  };

  stage(0, 0);
  __syncthreads();

  int cur = 0;
  for (int t = 0; t < nt; ++t) {
    if (t + 1 < nt) stage(cur ^ 1, t + 1);
#pragma unroll
    for (int kk = 0; kk < 2; ++kk) {
      short8 af[4], bfr[4];
#pragma unroll
      for (int mi = 0; mi < 4; ++mi) {
        const int r = wr * 64 + mi * 16 + lm;
        af[mi] = *reinterpret_cast<const short8*>(&Al[cur][r * BK + (((kk * 4 + lg) ^ XM(r)) * 8)]);
      }
#pragma unroll
      for (int ni = 0; ni < 4; ++ni) {
        const int r = colb[ni] + lm;
        bfr[ni] = *reinterpret_cast<const short8*>(&Bl[cur][r * BK + (((kk * 4 + lg) ^ XM(r)) * 8)]);
      }
#pragma unroll
      for (int mi = 0; mi < 4; ++mi)
#pragma unroll
        for (int ni = 0; ni < 4; ++ni)
          acc[mi][ni] = __builtin_amdgcn_mfma_f32_16x16x32_bf16(af[mi], bfr[ni], acc[mi][ni], 0, 0, 0);
    }
    __syncthreads();
    cur ^= 1;
  }

  // bias per ni (col-invariant over mi/r)
  float bb[4];
#pragma unroll
  for (int ni = 0; ni < 4; ++ni) bb[ni] = bias[bn + colb[ni] + lm];

  if (bn < 2560) {
    // Q (bn<2048) or K: bias -> RoPE -> (SC_Q for Q) -> scatter
    const bool isQ = (bn < 2048);
    const int head = isQ ? (bn >> 7) : ((bn - 2048) >> 7);
    const int nh = isQ ? H_ : KVH_;
    uint16_t* dst = isQ ? Qo : Ko;
    const float sc = isQ ? SC_Q : 1.0f;
#pragma unroll
    for (int mi = 0; mi < 4; ++mi) {
#pragma unroll
      for (int r = 0; r < 4; ++r) {
        const int row = bm + wr * 64 + mi * 16 + lg * 4 + r;
        const int b = row >> 11, tt = row & 2047;
        const float* cr = cosp + ((size_t)b * T_ + tt) * D_;
        const float* sr = sinp + ((size_t)b * T_ + tt) * D_;
        uint16_t* drow = dst + (((size_t)(b * nh + head)) * T_ + tt) * D_;
#pragma unroll
        for (int ni = 0; ni < 4; ++ni) {
          const int d = colb[ni] + lm;
          const float xv = acc[mi][ni][r] + bb[ni];
          const float pv = acc[mi][ni ^ 2][r] + bb[ni ^ 2];
          const float sgn = (ni < 2) ? -1.f : 1.f;  // ni<2 <=> d<64
          drow[d] = f2bf((xv * cr[d] + sgn * pv * sr[d]) * sc);
        }
      }
    }
  } else {
    // V: bias -> transposed write VtG[(b*4+kvh)*128+d][t], 4 bf16 packed (8B)
    const int kvh = (bn - 2560) >> 7;
#pragma unroll
    for (int mi = 0; mi < 4; ++mi) {
      const int row0 = bm + wr * 64 + mi * 16 + lg * 4;
      const int b = row0 >> 11, t0 = row0 & 2047;
#pragma unroll
      for (int ni = 0; ni < 4; ++ni) {
        const int d = colb[ni] + lm;
        union { uint16_t s[4]; uint2 u; } pk;
#pragma unroll
        for (int r = 0; r < 4; ++r) pk.s[r] = f2bf(acc[mi][ni][r] + bb[ni]);
        *reinterpret_cast<uint2*>(VtG + ((size_t)(b * KVH_ + kvh) * D_ + d) * T_ + t0) = pk.u;
      }
    }
  }
}

// ---------------- bt-GEMM (out-proj): A[M][K] bf16, Bt[N][K] bf16 -> C[M][N] f32 ----------------
__global__ __launch_bounds__(256, 2) void gemm_bt(const uint16_t* __restrict__ A,
                                                  const uint16_t* __restrict__ Bt,
                                                  float* __restrict__ Cv,
                                                  int M, int N, int K) {
  __shared__ __align__(16) uint16_t Al[2][BM * BK];
  __shared__ __align__(16) uint16_t Bl[2][BN * BK];
  const int tid = threadIdx.x;
  const int w = tid >> 6;
  const int lane = tid & 63;
  const int wr = w >> 1, wc = w & 1;
  const int lm = lane & 15, lg = lane >> 4;

  const int GX = gridDim.x;
  const int nwg = GX * gridDim.y;
  int bid = blockIdx.y * GX + blockIdx.x;
  bid = (bid & 7) * (nwg >> 3) + (bid >> 3);
  const int bm = (bid / GX) * BM;
  const int bn = (bid % GX) * BN;

  f32x4 acc[4][4];
  const f32x4 z4 = {0.f, 0.f, 0.f, 0.f};
#pragma unroll
  for (int i = 0; i < 4; ++i)
#pragma unroll
    for (int j = 0; j < 4; ++j) acc[i][j] = z4;

  const int nt = K >> 6;

  auto stage = [&](int b, int t) {
    const int k0 = t * BK;
#pragma unroll
    for (int it = 0; it < 4; ++it) {
      const int chunk = it * 256 + tid;
      const int r = chunk >> 3, c8 = chunk & 7;
      const int csw = (c8 ^ XM(r)) * 8;
      const uint16_t* gA = A + (size_t)(bm + r) * K + k0 + csw;
      const uint16_t* gB = Bt + (size_t)(bn + r) * K + k0 + csw;
      __builtin_amdgcn_global_load_lds((const __attribute__((address_space(1))) unsigned int*)gA,
                                       (__attribute__((address_space(3))) unsigned int*)(&Al[b][0] + chunk * 8),
                                       16, 0, 0);
      __builtin_amdgcn_global_load_lds((const __attribute__((address_space(1))) unsigned int*)gB,
                                       (__attribute__((address_space(3))) unsigned int*)(&Bl[b][0] + chunk * 8),
                                       16, 0, 0);
    }
  };

  stage(0, 0);
  __syncthreads();

  int cur = 0;
  for (int t = 0; t < nt; ++t) {
    if (t + 1 < nt) stage(cur ^ 1, t + 1);
#pragma unroll
    for (int kk = 0; kk < 2; ++kk) {
      short8 af[4], bfr[4];
#pragma unroll
      for (int mi = 0; mi < 4; ++mi) {
        const int r = wr * 64 + mi * 16 + lm;
        af[mi] = *reinterpret_cast<const short8*>(&Al[cur][r * BK + (((kk * 4 + lg) ^ XM(r)) * 8)]);
      }
#pragma unroll
      for (int ni = 0; ni < 4; ++ni) {
        const int r = wc * 64 + ni * 16 + lm;
        bfr[ni] = *reinterpret_cast<const short8*>(&Bl[cur][r * BK + (((kk * 4 + lg) ^ XM(r)) * 8)]);
      }
#pragma unroll
      for (int mi = 0; mi < 4; ++mi)
#pragma unroll
        for (int ni = 0; ni < 4; ++ni)
          acc[mi][ni] = __builtin_amdgcn_mfma_f32_16x16x32_bf16(af[mi], bfr[ni], acc[mi][ni], 0, 0, 0);
    }
    __syncthreads();
    cur ^= 1;
  }

#pragma unroll
  for (int mi = 0; mi < 4; ++mi) {
#pragma unroll
    for (int ni = 0; ni < 4; ++ni) {
      const int col = bn + wc * 64 + ni * 16 + lm;
#pragma unroll
      for (int r = 0; r < 4; ++r) {
        const int row = bm + wr * 64 + mi * 16 + lg * 4 + r;
        Cv[(size_t)row * N + col] = acc[mi][ni][r];
      }
    }
  }
}

// ---------------- causal GQA flash attention (paired q-tiles, K/V dbuf) ----------------
#define KVBLK 64

__global__ __launch_bounds__(256, 2) void attn_fwd(const uint16_t* __restrict__ Qb,
                                                   const uint16_t* __restrict__ Kb,
                                                   const uint16_t* __restrict__ VtG,
                                                   uint16_t* __restrict__ Ab) {
  __shared__ __align__(16) uint16_t Kl[2][KVBLK * D_];
  __shared__ __align__(16) uint16_t Vtl[2][D_ * KVBLK];
  __shared__ __align__(16) uint16_t Pl[4 * 16 * 64];
  const int tid = threadIdx.x;
  const int w = tid >> 6, lane = tid & 63;
  const int lm = lane & 15, lg = lane >> 4;
  const int bh = blockIdx.y;
  const int b = bh >> 4, h = bh & 15;
  const int kvh = h >> 2;
  const int qtA = (blockIdx.x + bh) & 15;
  const int qtB = 31 - qtA;
  const int nA = qtA + 1;
  const int ntot = 33;

  const uint16_t* Kbase = Kb + ((size_t)(b * KVH_ + kvh)) * T_ * D_;
  const uint16_t* Vtbase = VtG + ((size_t)(b * KVH_ + kvh)) * D_ * T_;
  uint16_t* Pw = Pl + w * 16 * 64;
  const f32x4 z4 = {0.f, 0.f, 0.f, 0.f};

  short8 vone;
#pragma unroll
  for (int j = 0; j < 8; ++j) vone[j] = (short)0x3F80;

  f32x4 o[8];
  f32x4 osum;
  float mrow[4];
  short8 qf[4];

  auto loadQ = [&](int qt) {
    const uint16_t* Qw = Qb + (((size_t)(b * H_ + h)) * T_ + qt * 64 + w * 16) * D_;
#pragma unroll
    for (int kk = 0; kk < 4; ++kk)
      qf[kk] = *reinterpret_cast<const short8*>(Qw + (size_t)lm * D_ + kk * 32 + lg * 8);
  };
  auto resetAcc = [&]() {
#pragma unroll
    for (int f = 0; f < 8; ++f) o[f] = z4;
    osum = z4;
#pragma unroll
    for (int r = 0; r < 4; ++r) mrow[r] = -1e30f;
  };
  auto flush = [&](int qt) {
    const int wr0 = qt * 64 + w * 16;
    float rcp[4];
#pragma unroll
    for (int r = 0; r < 4; ++r) rcp[r] = 1.0f / osum[r];
#pragma unroll
    for (int f = 0; f < 8; ++f) {
      const int col = h * D_ + f * 16 + lm;
#pragma unroll
      for (int r = 0; r < 4; ++r) {
        const int trow = wr0 + lg * 4 + r;
        Ab[((size_t)(b * T_ + trow)) * (H_ * D_) + col] = f2bf(o[f][r] * rcp[r]);
      }
    }
  };
  auto stage = [&](int buf, int kv0) {
#pragma unroll
    for (int it = 0; it < 4; ++it) {
      const int chunk = it * 256 + tid;
      {
        const int r = chunk >> 4, c16 = chunk & 15;
        const uint16_t* g = Kbase + (size_t)(kv0 + r) * D_ + ((c16 ^ XM(r)) * 8);
        __builtin_amdgcn_global_load_lds((const __attribute__((address_space(1))) unsigned int*)g,
                                         (__attribute__((address_space(3))) unsigned int*)(&Kl[buf][0] + (it * 256 + w * 64) * 8),
                                         16, 0, 0);
      }
      {
        const int dd = chunk >> 3, c8 = chunk & 7;
        const uint16_t* g = Vtbase + (size_t)dd * T_ + kv0 + ((c8 ^ XM(dd)) * 8);
        __builtin_amdgcn_global_load_lds((const __attribute__((address_space(1))) unsigned int*)g,
                                         (__attribute__((address_space(3))) unsigned int*)(&Vtl[buf][0] + (it * 256 + w * 64) * 8),
                                         16, 0, 0);
      }
    }
  };

  loadQ(qtA);
  resetAcc();
  stage(0, 0);
  __syncthreads();

  int cur = 0;
  for (int g = 0; g < ntot; ++g) {
    const bool inA = g < nA;
    const int t = inA ? g : g - nA;
    const int qt = inA ? qtA : qtB;
    const int kv0 = t * KVBLK;
    const int wrow0 = qt * 64 + w * 16;

    if (g + 1 < ntot) {
      const int gn = g + 1;
      const int kvn = (gn < nA ? gn : gn - nA) * KVBLK;
      stage(cur ^ 1, kvn);
    }

    f32x4 s[4];
#pragma unroll
    for (int nf = 0; nf < 4; ++nf) s[nf] = z4;
#pragma unroll
    for (int nf = 0; nf < 4; ++nf)
#pragma unroll
      for (int kk = 0; kk < 4; ++kk) {
        const int row = nf * 16 + lm;
        const short8 kf = *reinterpret_cast<const short8*>(&Kl[cur][row * D_ + (((kk * 4 + lg) ^ XM(row)) * 8)]);
        s[nf] = __builtin_amdgcn_mfma_f32_16x16x32_bf16(qf[kk], kf, s[nf], 0, 0, 0);
      }

    if (kv0 + KVBLK - 1 > wrow0) {
#pragma unroll
      for (int nf = 0; nf < 4; ++nf) {
        const int colg = kv0 + nf * 16 + lm;
#pragma unroll
        for (int r = 0; r < 4; ++r) {
          const int rowg = wrow0 + lg * 4 + r;
          if (colg > rowg) s[nf][r] = -1e30f;
        }
      }
    }

    float tmax[4];
#pragma unroll
    for (int r = 0; r < 4; ++r)
      tmax[r] = fmaxf(fmaxf(s[0][r], s[1][r]), fmaxf(s[2][r], s[3][r]));
    bool grow = false;
#pragma unroll
    for (int r = 0; r < 4; ++r) grow = grow || (tmax[r] > mrow[r] + 8.f);
    if (__any((int)grow)) {
#pragma unroll
      for (int r = 0; r < 4; ++r) {
        float v = tmax[r];
        v = fmaxf(v, __shfl_xor(v, 1));
        v = fmaxf(v, __shfl_xor(v, 2));
        v = fmaxf(v, __shfl_xor(v, 4));
        v = fmaxf(v, __shfl_xor(v, 8));
        const float nm = fmaxf(mrow[r], v);
        const float al = exp2f(mrow[r] - nm);
        mrow[r] = nm;
        osum[r] *= al;
#pragma unroll
        for (int f = 0; f < 8; ++f) o[f][r] *= al;
      }
    }
#pragma unroll
    for (int nf = 0; nf < 4; ++nf)
#pragma unroll
      for (int r = 0; r < 4; ++r) {
        const float p = exp2f(s[nf][r] - mrow[r]);
        const int prow = lg * 4 + r;
        const int pchunk = (nf * 2 + (lm >> 3)) ^ XM(prow);
        Pw[prow * 64 + pchunk * 8 + (lm & 7)] = hwbf(p);
      }
    asm volatile("s_waitcnt lgkmcnt(0)" ::: "memory");
    short8 pf[2];
#pragma unroll
    for (int ks = 0; ks < 2; ++ks)
      pf[ks] = *reinterpret_cast<const short8*>(Pw + lm * 64 + (((ks * 4 + lg) ^ XM(lm)) * 8));
#pragma unroll
    for (int ks = 0; ks < 2; ++ks)
      osum = __builtin_amdgcn_mfma_f32_16x16x32_bf16(pf[ks], vone, osum, 0, 0, 0);
#pragma unroll
    for (int f = 0; f < 8; ++f)
#pragma unroll
      for (int ks = 0; ks < 2; ++ks) {
        const int dd = f * 16 + lm;
        const short8 vf = *reinterpret_cast<const short8*>(&Vtl[cur][dd * KVBLK + (((ks * 4 + lg) ^ XM(dd)) * 8)]);
        o[f] = __builtin_amdgcn_mfma_f32_16x16x32_bf16(pf[ks], vf, o[f], 0, 0, 0);
      }

    __syncthreads();
    cur ^= 1;

    if (g == nA - 1) {
      flush(qtA);
      loadQ(qtB);
      resetAcc();
    }
  }
  flush(qtB);
}

// ---------------- launch ----------------
extern "C" void kernel_launch(void* const* d_in, const int* in_sizes, int n_in,
                              void* d_out, int out_size, void* d_ws, size_t ws_size,
                              hipStream_t stream) {
  const float* hidden = (const float*)d_in[0];
  const float* cosp   = (const float*)d_in[1];
  const float* sinp   = (const float*)d_in[2];
  // d_in[3] = attention_mask: exactly causal, implemented in-kernel
  const float* Wq = (const float*)d_in[4];
  const float* bq = (const float*)d_in[5];
  const float* Wk = (const float*)d_in[6];
  const float* bk = (const float*)d_in[7];
  const float* Wv = (const float*)d_in[8];
  const float* bv = (const float*)d_in[9];
  const float* Wo = (const float*)d_in[10];

  char* ws = (char*)d_ws;
  uint16_t* hidb   = (uint16_t*)(ws);              // 4096x2048 bf16   16,777,216 B
  uint16_t* wqkv   = (uint16_t*)(ws + 16777216);   // 3072x2048 bf16   12,582,912 B
  uint16_t* wob    = (uint16_t*)(ws + 29360128);   // 2048x2048 bf16    8,388,608 B
  float*    biasq  = (float*)   (ws + 37748736);   // 3072 f32             12,288 B
  uint16_t* Qb     = (uint16_t*)(ws + 62926848);   // [2][16][2048][128] 16,777,216 B
  uint16_t* Kb     = (uint16_t*)(ws + 79704064);   // [2][4][2048][128]   4,194,304 B
  uint16_t* VtG    = (uint16_t*)(ws + 83898368);   // [2][4][128][2048]   4,194,304 B
  uint16_t* Ab     = (uint16_t*)(ws + 88092672);   // [2][2048][2048]   16,777,216 B

  // one merged convert pass (hidden + Wq/Wk/Wv concat + Wo + bias concat)
  cvt_all<<<18432, 256, 0, stream>>>(hidden, Wq, Wk, Wv, Wo, bq, bk, bv,
                                     hidb, wqkv, wob, biasq);
  // QKV projection with fused bias+RoPE+scatter (+V transpose) epilogue
  gemm_qkv<<<dim3(24, 32), 256, 0, stream>>>(hidb, wqkv, biasq, cosp, sinp, Qb, Kb, VtG);
  // causal GQA flash attention -> Ab [b][t][h*128+d] bf16 (paired q-tiles)
  attn_fwd<<<dim3(16, 32), 256, 0, stream>>>(Qb, Kb, VtG, Ab);
  // output projection: [4096,2048] x [2048,2048]^T -> d_out fp32
  gemm_bt<<<dim3(16, 32), 256, 0, stream>>>(Ab, wob, (float*)d_out, 4096, 2048, 2048);
}

// Round 15
// 207.790 us; speedup vs baseline: 2.0067x; 1.0159x over previous
//
#include <hip/hip_runtime.h>
#include <hip/hip_bf16.h>
#include <stdint.h>

#define B_ 2
#define T_ 2048
#define HID_ 2048
#define H_ 16
#define KVH_ 4
#define D_ 128

typedef __attribute__((ext_vector_type(8))) short short8;
typedef __attribute__((ext_vector_type(4))) float f32x4;

__device__ __forceinline__ uint16_t f2bf(float x) {
  union { float f; uint32_t u; } c; c.f = x;
  uint32_t r = c.u + 0x7fffu + ((c.u >> 16) & 1u);
  return (uint16_t)(r >> 16);
}
__device__ __forceinline__ float bf2f(uint16_t b) {
  union { uint32_t u; float f; } c; c.u = ((uint32_t)b) << 16;
  return c.f;
}
__device__ __forceinline__ uint16_t hwbf(float x) {
  __hip_bfloat16 h = __float2bfloat16(x);
  return *reinterpret_cast<uint16_t*>(&h);
}

// chunk-XOR swizzle for LDS tiles (16B granules), de-aliases r and r+8
#define XM(r) (((r) & 7) ^ (((r) >> 1) & 4))
#define SC_Q 0.1275523865396698f  // 1/sqrt(128) * log2e

// ---------------- merged fp32->bf16 convert + bias concat (one launch) ----------------
__global__ __launch_bounds__(256) void cvt_all(const float* __restrict__ hidden,
                                               const float* __restrict__ Wq,
                                               const float* __restrict__ Wk,
                                               const float* __restrict__ Wv,
                                               const float* __restrict__ Wo,
                                               const float* __restrict__ bq,
                                               const float* __restrict__ bk,
                                               const float* __restrict__ bv,
                                               uint16_t* __restrict__ hidb,
                                               uint16_t* __restrict__ wqkv,
                                               uint16_t* __restrict__ wob,
                                               float* __restrict__ biasq) {
  const int gtid = blockIdx.x * 256 + threadIdx.x;
  const int i = gtid * 4;
  const float* src;
  uint16_t* dst;
  if (i < 8388608)       { src = hidden + i;            dst = hidb + i; }
  else if (i < 12582912) { src = Wq + (i - 8388608);    dst = wqkv + (i - 8388608); }
  else if (i < 13631488) { src = Wk + (i - 12582912);   dst = wqkv + 4194304 + (i - 12582912); }
  else if (i < 14680064) { src = Wv + (i - 13631488);   dst = wqkv + 5242880 + (i - 13631488); }
  else                   { src = Wo + (i - 14680064);   dst = wob + (i - 14680064); }
  const float4 v = *reinterpret_cast<const float4*>(src);
  union { uint16_t s[4]; uint2 u; } pk;
  pk.s[0] = f2bf(v.x); pk.s[1] = f2bf(v.y); pk.s[2] = f2bf(v.z); pk.s[3] = f2bf(v.w);
  *reinterpret_cast<uint2*>(dst) = pk.u;
  if (gtid < 3072)
    biasq[gtid] = (gtid < 2048) ? bq[gtid] : (gtid < 2560) ? bk[gtid - 2048] : bv[gtid - 2560];
}

// ---------------- QKV GEMM (512 threads, 8 waves) with fused RoPE epilogue ----------------
// 128x128 tile, BK=64, 8 waves as 4M x 2N (wave tile 32x64, acc[2][4]).
// Waves/CU 8->16 at same LDS (64KB, 2 blocks/CU) -> 2x TLP for latency hiding.
#define BM 128
#define BN 128
#define BK 64

__global__ __launch_bounds__(512, 4) void gemm_qkv(const uint16_t* __restrict__ A,
                                                   const uint16_t* __restrict__ Bt,
                                                   const float* __restrict__ bias,
                                                   const float* __restrict__ cosp,
                                                   const float* __restrict__ sinp,
                                                   uint16_t* __restrict__ Qo,
                                                   uint16_t* __restrict__ Ko,
                                                   uint16_t* __restrict__ VtG) {
  __shared__ __align__(16) uint16_t Al[2][BM * BK];
  __shared__ __align__(16) uint16_t Bl[2][BN * BK];
  const int K = 2048;
  const int tid = threadIdx.x;
  const int w = tid >> 6;
  const int lane = tid & 63;
  const int wr = w >> 1, wc = w & 1;     // 4 M-waves x 2 N-waves
  const int lm = lane & 15, lg = lane >> 4;

  const int GX = gridDim.x;
  const int nwg = GX * gridDim.y;
  int bid = blockIdx.y * GX + blockIdx.x;
  bid = (bid & 7) * (nwg >> 3) + (bid >> 3);
  const int bm = (bid / GX) * BM;
  const int bn = (bid % GX) * BN;

  // B-frag col-base per ni: RoPE partner (d^64) is frag ni^2, same thread
  const int colb[4] = {wc * 32, wc * 32 + 16, wc * 32 + 64, wc * 32 + 80};

  f32x4 acc[2][4];
  const f32x4 z4 = {0.f, 0.f, 0.f, 0.f};
#pragma unroll
  for (int i = 0; i < 2; ++i)
#pragma unroll
    for (int j = 0; j < 4; ++j) acc[i][j] = z4;

  const int nt = K >> 6;

  auto stage = [&](int b, int t) {
    const int k0 = t * BK;
#pragma unroll
    for (int it = 0; it < 2; ++it) {
      const int chunk = it * 512 + tid;          // 0..1023 (row r, 16B chunk c8)
      const int r = chunk >> 3, c8 = chunk & 7;
      const int csw = (c8 ^ XM(r)) * 8;
      const uint16_t* gA = A + (size_t)(bm + r) * K + k0 + csw;
      const uint16_t* gB = Bt + (size_t)(bn + r) * K + k0 + csw;
      __builtin_amdgcn_global_load_lds((const __attribute__((address_space(1))) unsigned int*)gA,
                                       (__attribute__((address_space(3))) unsigned int*)(&Al[b][0] + chunk * 8),
                                       16, 0, 0);
      __builtin_amdgcn_global_load_lds((const __attribute__((address_space(1))) unsigned int*)gB,
                                       (__attribute__((address_space(3))) unsigned int*)(&Bl[b][0] + chunk * 8),
                                       16, 0, 0);
    }
  };

  stage(0, 0);
  __syncthreads();

  int cur = 0;
  for (int t = 0; t < nt; ++t) {
    if (t + 1 < nt) stage(cur ^ 1, t + 1);
#pragma unroll
    for (int kk = 0; kk < 2; ++kk) {
      short8 af[2], bfr[4];
#pragma unroll
      for (int mi = 0; mi < 2; ++mi) {
        const int r = wr * 32 + mi * 16 + lm;
        af[mi] = *reinterpret_cast<const short8*>(&Al[cur][r * BK + (((kk * 4 + lg) ^ XM(r)) * 8)]);
      }
#pragma unroll
      for (int ni = 0; ni < 4; ++ni) {
        const int r = colb[ni] + lm;
        bfr[ni] = *reinterpret_cast<const short8*>(&Bl[cur][r * BK + (((kk * 4 + lg) ^ XM(r)) * 8)]);
      }
#pragma unroll
      for (int mi = 0; mi < 2; ++mi)
#pragma unroll
        for (int ni = 0; ni < 4; ++ni)
          acc[mi][ni] = __builtin_amdgcn_mfma_f32_16x16x32_bf16(af[mi], bfr[ni], acc[mi][ni], 0, 0, 0);
    }
    __syncthreads();
    cur ^= 1;
  }

  float bb[4];
#pragma unroll
  for (int ni = 0; ni < 4; ++ni) bb[ni] = bias[bn + colb[ni] + lm];

  if (bn < 2560) {
    const bool isQ = (bn < 2048);
    const int head = isQ ? (bn >> 7) : ((bn - 2048) >> 7);
    const int nh = isQ ? H_ : KVH_;
    uint16_t* dst = isQ ? Qo : Ko;
    const float sc = isQ ? SC_Q : 1.0f;
#pragma unroll
    for (int mi = 0; mi < 2; ++mi) {
#pragma unroll
      for (int r = 0; r < 4; ++r) {
        const int row = bm + wr * 32 + mi * 16 + lg * 4 + r;
        const int b = row >> 11, tt = row & 2047;
        const float* cr = cosp + ((size_t)b * T_ + tt) * D_;
        const float* sr = sinp + ((size_t)b * T_ + tt) * D_;
        uint16_t* drow = dst + (((size_t)(b * nh + head)) * T_ + tt) * D_;
#pragma unroll
        for (int ni = 0; ni < 4; ++ni) {
          const int d = colb[ni] + lm;
          const float xv = acc[mi][ni][r] + bb[ni];
          const float pv = acc[mi][ni ^ 2][r] + bb[ni ^ 2];
          const float sgn = (ni < 2) ? -1.f : 1.f;  // ni<2 <=> d<64
          drow[d] = f2bf((xv * cr[d] + sgn * pv * sr[d]) * sc);
        }
      }
    }
  } else {
    const int kvh = (bn - 2560) >> 7;
#pragma unroll
    for (int mi = 0; mi < 2; ++mi) {
      const int row0 = bm + wr * 32 + mi * 16 + lg * 4;
      const int b = row0 >> 11, t0 = row0 & 2047;
#pragma unroll
      for (int ni = 0; ni < 4; ++ni) {
        const int d = colb[ni] + lm;
        union { uint16_t s[4]; uint2 u; } pk;
#pragma unroll
        for (int r = 0; r < 4; ++r) pk.s[r] = f2bf(acc[mi][ni][r] + bb[ni]);
        *reinterpret_cast<uint2*>(VtG + ((size_t)(b * KVH_ + kvh) * D_ + d) * T_ + t0) = pk.u;
      }
    }
  }
}

// ---------------- out-proj GEMM (512 threads, 8 waves): C[M][N] f32 ----------------
__global__ __launch_bounds__(512, 4) void gemm_bt(const uint16_t* __restrict__ A,
                                                  const uint16_t* __restrict__ Bt,
                                                  float* __restrict__ Cv,
                                                  int M, int N, int K) {
  __shared__ __align__(16) uint16_t Al[2][BM * BK];
  __shared__ __align__(16) uint16_t Bl[2][BN * BK];
  const int tid = threadIdx.x;
  const int w = tid >> 6;
  const int lane = tid & 63;
  const int wr = w >> 1, wc = w & 1;
  const int lm = lane & 15, lg = lane >> 4;

  const int GX = gridDim.x;
  const int nwg = GX * gridDim.y;
  int bid = blockIdx.y * GX + blockIdx.x;
  bid = (bid & 7) * (nwg >> 3) + (bid >> 3);
  const int bm = (bid / GX) * BM;
  const int bn = (bid % GX) * BN;

  f32x4 acc[2][4];
  const f32x4 z4 = {0.f, 0.f, 0.f, 0.f};
#pragma unroll
  for (int i = 0; i < 2; ++i)
#pragma unroll
    for (int j = 0; j < 4; ++j) acc[i][j] = z4;

  const int nt = K >> 6;

  auto stage = [&](int b, int t) {
    const int k0 = t * BK;
#pragma unroll
    for (int it = 0; it < 2; ++it) {
      const int chunk = it * 512 + tid;
      const int r = chunk >> 3, c8 = chunk & 7;
      const int csw = (c8 ^ XM(r)) * 8;
      const uint16_t* gA = A + (size_t)(bm + r) * K + k0 + csw;
      const uint16_t* gB = Bt + (size_t)(bn + r) * K + k0 + csw;
      __builtin_amdgcn_global_load_lds((const __attribute__((address_space(1))) unsigned int*)gA,
                                       (__attribute__((address_space(3))) unsigned int*)(&Al[b][0] + chunk * 8),
                                       16, 0, 0);
      __builtin_amdgcn_global_load_lds((const __attribute__((address_space(1))) unsigned int*)gB,
                                       (__attribute__((address_space(3))) unsigned int*)(&Bl[b][0] + chunk * 8),
                                       16, 0, 0);
    }
  };

  stage(0, 0);
  __syncthreads();

  int cur = 0;
  for (int t = 0; t < nt; ++t) {
    if (t + 1 < nt) stage(cur ^ 1, t + 1);
#pragma unroll
    for (int kk = 0; kk < 2; ++kk) {
      short8 af[2], bfr[4];
#pragma unroll
      for (int mi = 0; mi < 2; ++mi) {
        const int r = wr * 32 + mi * 16 + lm;
        af[mi] = *reinterpret_cast<const short8*>(&Al[cur][r * BK + (((kk * 4 + lg) ^ XM(r)) * 8)]);
      }
#pragma unroll
      for (int ni = 0; ni < 4; ++ni) {
        const int r = wc * 64 + ni * 16 + lm;
        bfr[ni] = *reinterpret_cast<const short8*>(&Bl[cur][r * BK + (((kk * 4 + lg) ^ XM(r)) * 8)]);
      }
#pragma unroll
      for (int mi = 0; mi < 2; ++mi)
#pragma unroll
        for (int ni = 0; ni < 4; ++ni)
          acc[mi][ni] = __builtin_amdgcn_mfma_f32_16x16x32_bf16(af[mi], bfr[ni], acc[mi][ni], 0, 0, 0);
    }
    __syncthreads();
    cur ^= 1;
  }

#pragma unroll
  for (int mi = 0; mi < 2; ++mi) {
#pragma unroll
    for (int ni = 0; ni < 4; ++ni) {
      const int col = bn + wc * 64 + ni * 16 + lm;
#pragma unroll
      for (int r = 0; r < 4; ++r) {
        const int row = bm + wr * 32 + mi * 16 + lg * 4 + r;
        Cv[(size_t)row * N + col] = acc[mi][ni][r];
      }
    }
  }
}

// ---------------- causal GQA flash attention (paired q-tiles, K/V dbuf) ----------------
#define KVBLK 64

__global__ __launch_bounds__(256, 2) void attn_fwd(const uint16_t* __restrict__ Qb,
                                                   const uint16_t* __restrict__ Kb,
                                                   const uint16_t* __restrict__ VtG,
                                                   uint16_t* __restrict__ Ab) {
  __shared__ __align__(16) uint16_t Kl[2][KVBLK * D_];
  __shared__ __align__(16) uint16_t Vtl[2][D_ * KVBLK];
  __shared__ __align__(16) uint16_t Pl[4 * 16 * 64];
  const int tid = threadIdx.x;
  const int w = tid >> 6, lane = tid & 63;
  const int lm = lane & 15, lg = lane >> 4;
  const int bh = blockIdx.y;
  const int b = bh >> 4, h = bh & 15;
  const int kvh = h >> 2;
  const int qtA = (blockIdx.x + bh) & 15;
  const int qtB = 31 - qtA;
  const int nA = qtA + 1;
  const int ntot = 33;

  const uint16_t* Kbase = Kb + ((size_t)(b * KVH_ + kvh)) * T_ * D_;
  const uint16_t* Vtbase = VtG + ((size_t)(b * KVH_ + kvh)) * D_ * T_;
  uint16_t* Pw = Pl + w * 16 * 64;
  const f32x4 z4 = {0.f, 0.f, 0.f, 0.f};

  short8 vone;
#pragma unroll
  for (int j = 0; j < 8; ++j) vone[j] = (short)0x3F80;

  f32x4 o[8];
  f32x4 osum;
  float mrow[4];
  short8 qf[4];

  auto loadQ = [&](int qt) {
    const uint16_t* Qw = Qb + (((size_t)(b * H_ + h)) * T_ + qt * 64 + w * 16) * D_;
#pragma unroll
    for (int kk = 0; kk < 4; ++kk)
      qf[kk] = *reinterpret_cast<const short8*>(Qw + (size_t)lm * D_ + kk * 32 + lg * 8);
  };
  auto resetAcc = [&]() {
#pragma unroll
    for (int f = 0; f < 8; ++f) o[f] = z4;
    osum = z4;
#pragma unroll
    for (int r = 0; r < 4; ++r) mrow[r] = -1e30f;
  };
  auto flush = [&](int qt) {
    const int wr0 = qt * 64 + w * 16;
    float rcp[4];
#pragma unroll
    for (int r = 0; r < 4; ++r) rcp[r] = 1.0f / osum[r];
#pragma unroll
    for (int f = 0; f < 8; ++f) {
      const int col = h * D_ + f * 16 + lm;
#pragma unroll
      for (int r = 0; r < 4; ++r) {
        const int trow = wr0 + lg * 4 + r;
        Ab[((size_t)(b * T_ + trow)) * (H_ * D_) + col] = f2bf(o[f][r] * rcp[r]);
      }
    }
  };
  auto stage = [&](int buf, int kv0) {
#pragma unroll
    for (int it = 0; it < 4; ++it) {
      const int chunk = it * 256 + tid;
      {
        const int r = chunk >> 4, c16 = chunk & 15;
        const uint16_t* g = Kbase + (size_t)(kv0 + r) * D_ + ((c16 ^ XM(r)) * 8);
        __builtin_amdgcn_global_load_lds((const __attribute__((address_space(1))) unsigned int*)g,
                                         (__attribute__((address_space(3))) unsigned int*)(&Kl[buf][0] + (it * 256 + w * 64) * 8),
                                         16, 0, 0);
      }
      {
        const int dd = chunk >> 3, c8 = chunk & 7;
        const uint16_t* g = Vtbase + (size_t)dd * T_ + kv0 + ((c8 ^ XM(dd)) * 8);
        __builtin_amdgcn_global_load_lds((const __attribute__((address_space(1))) unsigned int*)g,
                                         (__attribute__((address_space(3))) unsigned int*)(&Vtl[buf][0] + (it * 256 + w * 64) * 8),
                                         16, 0, 0);
      }
    }
  };

  loadQ(qtA);
  resetAcc();
  stage(0, 0);
  __syncthreads();

  int cur = 0;
  for (int g = 0; g < ntot; ++g) {
    const bool inA = g < nA;
    const int t = inA ? g : g - nA;
    const int qt = inA ? qtA : qtB;
    const int kv0 = t * KVBLK;
    const int wrow0 = qt * 64 + w * 16;

    if (g + 1 < ntot) {
      const int gn = g + 1;
      const int kvn = (gn < nA ? gn : gn - nA) * KVBLK;
      stage(cur ^ 1, kvn);
    }

    f32x4 s[4];
#pragma unroll
    for (int nf = 0; nf < 4; ++nf) s[nf] = z4;
#pragma unroll
    for (int nf = 0; nf < 4; ++nf)
#pragma unroll
      for (int kk = 0; kk < 4; ++kk) {
        const int row = nf * 16 + lm;
        const short8 kf = *reinterpret_cast<const short8*>(&Kl[cur][row * D_ + (((kk * 4 + lg) ^ XM(row)) * 8)]);
        s[nf] = __builtin_amdgcn_mfma_f32_16x16x32_bf16(qf[kk], kf, s[nf], 0, 0, 0);
      }

    if (kv0 + KVBLK - 1 > wrow0) {
#pragma unroll
      for (int nf = 0; nf < 4; ++nf) {
        const int colg = kv0 + nf * 16 + lm;
#pragma unroll
        for (int r = 0; r < 4; ++r) {
          const int rowg = wrow0 + lg * 4 + r;
          if (colg > rowg) s[nf][r] = -1e30f;
        }
      }
    }

    float tmax[4];
#pragma unroll
    for (int r = 0; r < 4; ++r)
      tmax[r] = fmaxf(fmaxf(s[0][r], s[1][r]), fmaxf(s[2][r], s[3][r]));
    bool grow = false;
#pragma unroll
    for (int r = 0; r < 4; ++r) grow = grow || (tmax[r] > mrow[r] + 8.f);
    if (__any((int)grow)) {
#pragma unroll
      for (int r = 0; r < 4; ++r) {
        float v = tmax[r];
        v = fmaxf(v, __shfl_xor(v, 1));
        v = fmaxf(v, __shfl_xor(v, 2));
        v = fmaxf(v, __shfl_xor(v, 4));
        v = fmaxf(v, __shfl_xor(v, 8));
        const float nm = fmaxf(mrow[r], v);
        const float al = exp2f(mrow[r] - nm);
        mrow[r] = nm;
        osum[r] *= al;
#pragma unroll
        for (int f = 0; f < 8; ++f) o[f][r] *= al;
      }
    }
#pragma unroll
    for (int nf = 0; nf < 4; ++nf)
#pragma unroll
      for (int r = 0; r < 4; ++r) {
        const float p = exp2f(s[nf][r] - mrow[r]);
        const int prow = lg * 4 + r;
        const int pchunk = (nf * 2 + (lm >> 3)) ^ XM(prow);
        Pw[prow * 64 + pchunk * 8 + (lm & 7)] = hwbf(p);
      }
    asm volatile("s_waitcnt lgkmcnt(0)" ::: "memory");
    short8 pf[2];
#pragma unroll
    for (int ks = 0; ks < 2; ++ks)
      pf[ks] = *reinterpret_cast<const short8*>(Pw + lm * 64 + (((ks * 4 + lg) ^ XM(lm)) * 8));
#pragma unroll
    for (int ks = 0; ks < 2; ++ks)
      osum = __builtin_amdgcn_mfma_f32_16x16x32_bf16(pf[ks], vone, osum, 0, 0, 0);
#pragma unroll
    for (int f = 0; f < 8; ++f)
#pragma unroll
      for (int ks = 0; ks < 2; ++ks) {
        const int dd = f * 16 + lm;
        const short8 vf = *reinterpret_cast<const short8*>(&Vtl[cur][dd * KVBLK + (((ks * 4 + lg) ^ XM(dd)) * 8)]);
        o[f] = __builtin_amdgcn_mfma_f32_16x16x32_bf16(pf[ks], vf, o[f], 0, 0, 0);
      }

    __syncthreads();
    cur ^= 1;

    if (g == nA - 1) {
      flush(qtA);
      loadQ(qtB);
      resetAcc();
    }
  }
  flush(qtB);
}

// ---------------- launch ----------------
extern "C" void kernel_launch(void* const* d_in, const int* in_sizes, int n_in,
                              void* d_out, int out_size, void* d_ws, size_t ws_size,
                              hipStream_t stream) {
  const float* hidden = (const float*)d_in[0];
  const float* cosp   = (const float*)d_in[1];
  const float* sinp   = (const float*)d_in[2];
  // d_in[3] = attention_mask: exactly causal, implemented in-kernel
  const float* Wq = (const float*)d_in[4];
  const float* bq = (const float*)d_in[5];
  const float* Wk = (const float*)d_in[6];
  const float* bk = (const float*)d_in[7];
  const float* Wv = (const float*)d_in[8];
  const float* bv = (const float*)d_in[9];
  const float* Wo = (const float*)d_in[10];

  char* ws = (char*)d_ws;
  uint16_t* hidb   = (uint16_t*)(ws);              // 4096x2048 bf16   16,777,216 B
  uint16_t* wqkv   = (uint16_t*)(ws + 16777216);   // 3072x2048 bf16   12,582,912 B
  uint16_t* wob    = (uint16_t*)(ws + 29360128);   // 2048x2048 bf16    8,388,608 B
  float*    biasq  = (float*)   (ws + 37748736);   // 3072 f32             12,288 B
  uint16_t* Qb     = (uint16_t*)(ws + 62926848);   // [2][16][2048][128] 16,777,216 B
  uint16_t* Kb     = (uint16_t*)(ws + 79704064);   // [2][4][2048][128]   4,194,304 B
  uint16_t* VtG    = (uint16_t*)(ws + 83898368);   // [2][4][128][2048]   4,194,304 B
  uint16_t* Ab     = (uint16_t*)(ws + 88092672);   // [2][2048][2048]   16,777,216 B

  // one merged convert pass (hidden + Wq/Wk/Wv concat + Wo + bias concat)
  cvt_all<<<18432, 256, 0, stream>>>(hidden, Wq, Wk, Wv, Wo, bq, bk, bv,
                                     hidb, wqkv, wob, biasq);
  // QKV projection with fused bias+RoPE+scatter (+V transpose) epilogue
  gemm_qkv<<<dim3(24, 32), 512, 0, stream>>>(hidb, wqkv, biasq, cosp, sinp, Qb, Kb, VtG);
  // causal GQA flash attention -> Ab [b][t][h*128+d] bf16 (paired q-tiles)
  attn_fwd<<<dim3(16, 32), 256, 0, stream>>>(Qb, Kb, VtG, Ab);
  // output projection: [4096,2048] x [2048,2048]^T -> d_out fp32
  gemm_bt<<<dim3(16, 32), 512, 0, stream>>>(Ab, wob, (float*)d_out, 4096, 2048, 2048);
}

// Round 16
// 207.377 us; speedup vs baseline: 2.0107x; 1.0020x over previous
//
#include <hip/hip_runtime.h>
#include <hip/hip_bf16.h>
#include <stdint.h>

#define B_ 2
#define T_ 2048
#define HID_ 2048
#define H_ 16
#define KVH_ 4
#define D_ 128

typedef __attribute__((ext_vector_type(8))) short short8;
typedef __attribute__((ext_vector_type(4))) float f32x4;

__device__ __forceinline__ uint16_t f2bf(float x) {
  union { float f; uint32_t u; } c; c.f = x;
  uint32_t r = c.u + 0x7fffu + ((c.u >> 16) & 1u);
  return (uint16_t)(r >> 16);
}
__device__ __forceinline__ float bf2f(uint16_t b) {
  union { uint32_t u; float f; } c; c.u = ((uint32_t)b) << 16;
  return c.f;
}
__device__ __forceinline__ uint16_t hwbf(float x) {
  __hip_bfloat16 h = __float2bfloat16(x);
  return *reinterpret_cast<uint16_t*>(&h);
}

// chunk-XOR swizzle for LDS tiles (16B granules), de-aliases r and r+8
#define XM(r) (((r) & 7) ^ (((r) >> 1) & 4))
#define SC_Q 0.1275523865396698f  // 1/sqrt(128) * log2e

// ---------------- merged fp32->bf16 convert + bias concat (one launch) ----------------
__global__ __launch_bounds__(256) void cvt_all(const float* __restrict__ hidden,
                                               const float* __restrict__ Wq,
                                               const float* __restrict__ Wk,
                                               const float* __restrict__ Wv,
                                               const float* __restrict__ Wo,
                                               const float* __restrict__ bq,
                                               const float* __restrict__ bk,
                                               const float* __restrict__ bv,
                                               uint16_t* __restrict__ hidb,
                                               uint16_t* __restrict__ wqkv,
                                               uint16_t* __restrict__ wob,
                                               float* __restrict__ biasq) {
  const int gtid = blockIdx.x * 256 + threadIdx.x;
  const int i = gtid * 4;
  const float* src;
  uint16_t* dst;
  if (i < 8388608)       { src = hidden + i;            dst = hidb + i; }
  else if (i < 12582912) { src = Wq + (i - 8388608);    dst = wqkv + (i - 8388608); }
  else if (i < 13631488) { src = Wk + (i - 12582912);   dst = wqkv + 4194304 + (i - 12582912); }
  else if (i < 14680064) { src = Wv + (i - 13631488);   dst = wqkv + 5242880 + (i - 13631488); }
  else                   { src = Wo + (i - 14680064);   dst = wob + (i - 14680064); }
  const float4 v = *reinterpret_cast<const float4*>(src);
  union { uint16_t s[4]; uint2 u; } pk;
  pk.s[0] = f2bf(v.x); pk.s[1] = f2bf(v.y); pk.s[2] = f2bf(v.z); pk.s[3] = f2bf(v.w);
  *reinterpret_cast<uint2*>(dst) = pk.u;
  if (gtid < 3072)
    biasq[gtid] = (gtid < 2048) ? bq[gtid] : (gtid < 2560) ? bk[gtid - 2048] : bv[gtid - 2560];
}

// 2D XCD chunk map: each XCD owns an 8-Mrow x (GX/2)-Ncol chunk; within a
// chunk iterate M-fastest so each 512KB B-panel is reused 8x back-to-back.
// Requires gridDim.y == 32 and GX even. Bijective.
__device__ __forceinline__ void xcd_chunk_2d(int GX, int& bm_t, int& bn_t) {
  const int orig = blockIdx.y * GX + blockIdx.x;
  const int xcd = orig & 7;
  const int c = orig >> 3;
  bm_t = (xcd >> 1) * 8 + (c & 7);
  bn_t = (xcd & 1) * (GX >> 1) + (c >> 3);
}

// ---------------- QKV GEMM (512 threads, 8 waves) with fused RoPE epilogue ----------------
#define BM 128
#define BN 128
#define BK 64

__global__ __launch_bounds__(512, 4) void gemm_qkv(const uint16_t* __restrict__ A,
                                                   const uint16_t* __restrict__ Bt,
                                                   const float* __restrict__ bias,
                                                   const float* __restrict__ cosp,
                                                   const float* __restrict__ sinp,
                                                   uint16_t* __restrict__ Qo,
                                                   uint16_t* __restrict__ Ko,
                                                   uint16_t* __restrict__ VtG) {
  __shared__ __align__(16) uint16_t Al[2][BM * BK];
  __shared__ __align__(16) uint16_t Bl[2][BN * BK];
  const int K = 2048;
  const int tid = threadIdx.x;
  const int w = tid >> 6;
  const int lane = tid & 63;
  const int wr = w >> 1, wc = w & 1;     // 4 M-waves x 2 N-waves
  const int lm = lane & 15, lg = lane >> 4;

  int bm_t, bn_t;
  xcd_chunk_2d(gridDim.x, bm_t, bn_t);
  const int bm = bm_t * BM;
  const int bn = bn_t * BN;

  // B-frag col-base per ni: RoPE partner (d^64) is frag ni^2, same thread
  const int colb[4] = {wc * 32, wc * 32 + 16, wc * 32 + 64, wc * 32 + 80};

  f32x4 acc[2][4];
  const f32x4 z4 = {0.f, 0.f, 0.f, 0.f};
#pragma unroll
  for (int i = 0; i < 2; ++i)
#pragma unroll
    for (int j = 0; j < 4; ++j) acc[i][j] = z4;

  const int nt = K >> 6;

  auto stage = [&](int b, int t) {
    const int k0 = t * BK;
#pragma unroll
    for (int it = 0; it < 2; ++it) {
      const int chunk = it * 512 + tid;          // 0..1023 (row r, 16B chunk c8)
      const int r = chunk >> 3, c8 = chunk & 7;
      const int csw = (c8 ^ XM(r)) * 8;
      const uint16_t* gA = A + (size_t)(bm + r) * K + k0 + csw;
      const uint16_t* gB = Bt + (size_t)(bn + r) * K + k0 + csw;
      __builtin_amdgcn_global_load_lds((const __attribute__((address_space(1))) unsigned int*)gA,
                                       (__attribute__((address_space(3))) unsigned int*)(&Al[b][0] + chunk * 8),
                                       16, 0, 0);
      __builtin_amdgcn_global_load_lds((const __attribute__((address_space(1))) unsigned int*)gB,
                                       (__attribute__((address_space(3))) unsigned int*)(&Bl[b][0] + chunk * 8),
                                       16, 0, 0);
    }
  };

  stage(0, 0);
  __syncthreads();

  int cur = 0;
  for (int t = 0; t < nt; ++t) {
    if (t + 1 < nt) stage(cur ^ 1, t + 1);
#pragma unroll
    for (int kk = 0; kk < 2; ++kk) {
      short8 af[2], bfr[4];
#pragma unroll
      for (int mi = 0; mi < 2; ++mi) {
        const int r = wr * 32 + mi * 16 + lm;
        af[mi] = *reinterpret_cast<const short8*>(&Al[cur][r * BK + (((kk * 4 + lg) ^ XM(r)) * 8)]);
      }
#pragma unroll
      for (int ni = 0; ni < 4; ++ni) {
        const int r = colb[ni] + lm;
        bfr[ni] = *reinterpret_cast<const short8*>(&Bl[cur][r * BK + (((kk * 4 + lg) ^ XM(r)) * 8)]);
      }
#pragma unroll
      for (int mi = 0; mi < 2; ++mi)
#pragma unroll
        for (int ni = 0; ni < 4; ++ni)
          acc[mi][ni] = __builtin_amdgcn_mfma_f32_16x16x32_bf16(af[mi], bfr[ni], acc[mi][ni], 0, 0, 0);
    }
    __syncthreads();
    cur ^= 1;
  }

  float bb[4];
#pragma unroll
  for (int ni = 0; ni < 4; ++ni) bb[ni] = bias[bn + colb[ni] + lm];

  if (bn < 2560) {
    const bool isQ = (bn < 2048);
    const int head = isQ ? (bn >> 7) : ((bn - 2048) >> 7);
    const int nh = isQ ? H_ : KVH_;
    uint16_t* dst = isQ ? Qo : Ko;
    const float sc = isQ ? SC_Q : 1.0f;
#pragma unroll
    for (int mi = 0; mi < 2; ++mi) {
#pragma unroll
      for (int r = 0; r < 4; ++r) {
        const int row = bm + wr * 32 + mi * 16 + lg * 4 + r;
        const int b = row >> 11, tt = row & 2047;
        const float* cr = cosp + ((size_t)b * T_ + tt) * D_;
        const float* sr = sinp + ((size_t)b * T_ + tt) * D_;
        uint16_t* drow = dst + (((size_t)(b * nh + head)) * T_ + tt) * D_;
#pragma unroll
        for (int ni = 0; ni < 4; ++ni) {
          const int d = colb[ni] + lm;
          const float xv = acc[mi][ni][r] + bb[ni];
          const float pv = acc[mi][ni ^ 2][r] + bb[ni ^ 2];
          const float sgn = (ni < 2) ? -1.f : 1.f;  // ni<2 <=> d<64
          drow[d] = f2bf((xv * cr[d] + sgn * pv * sr[d]) * sc);
        }
      }
    }
  } else {
    const int kvh = (bn - 2560) >> 7;
#pragma unroll
    for (int mi = 0; mi < 2; ++mi) {
      const int row0 = bm + wr * 32 + mi * 16 + lg * 4;
      const int b = row0 >> 11, t0 = row0 & 2047;
#pragma unroll
      for (int ni = 0; ni < 4; ++ni) {
        const int d = colb[ni] + lm;
        union { uint16_t s[4]; uint2 u; } pk;
#pragma unroll
        for (int r = 0; r < 4; ++r) pk.s[r] = f2bf(acc[mi][ni][r] + bb[ni]);
        *reinterpret_cast<uint2*>(VtG + ((size_t)(b * KVH_ + kvh) * D_ + d) * T_ + t0) = pk.u;
      }
    }
  }
}

// ---------------- out-proj GEMM (512 threads, 8 waves): C[M][N] f32 ----------------
__global__ __launch_bounds__(512, 4) void gemm_bt(const uint16_t* __restrict__ A,
                                                  const uint16_t* __restrict__ Bt,
                                                  float* __restrict__ Cv,
                                                  int M, int N, int K) {
  __shared__ __align__(16) uint16_t Al[2][BM * BK];
  __shared__ __align__(16) uint16_t Bl[2][BN * BK];
  const int tid = threadIdx.x;
  const int w = tid >> 6;
  const int lane = tid & 63;
  const int wr = w >> 1, wc = w & 1;
  const int lm = lane & 15, lg = lane >> 4;

  int bm_t, bn_t;
  xcd_chunk_2d(gridDim.x, bm_t, bn_t);
  const int bm = bm_t * BM;
  const int bn = bn_t * BN;

  f32x4 acc[2][4];
  const f32x4 z4 = {0.f, 0.f, 0.f, 0.f};
#pragma unroll
  for (int i = 0; i < 2; ++i)
#pragma unroll
    for (int j = 0; j < 4; ++j) acc[i][j] = z4;

  const int nt = K >> 6;

  auto stage = [&](int b, int t) {
    const int k0 = t * BK;
#pragma unroll
    for (int it = 0; it < 2; ++it) {
      const int chunk = it * 512 + tid;
      const int r = chunk >> 3, c8 = chunk & 7;
      const int csw = (c8 ^ XM(r)) * 8;
      const uint16_t* gA = A + (size_t)(bm + r) * K + k0 + csw;
      const uint16_t* gB = Bt + (size_t)(bn + r) * K + k0 + csw;
      __builtin_amdgcn_global_load_lds((const __attribute__((address_space(1))) unsigned int*)gA,
                                       (__attribute__((address_space(3))) unsigned int*)(&Al[b][0] + chunk * 8),
                                       16, 0, 0);
      __builtin_amdgcn_global_load_lds((const __attribute__((address_space(1))) unsigned int*)gB,
                                       (__attribute__((address_space(3))) unsigned int*)(&Bl[b][0] + chunk * 8),
                                       16, 0, 0);
    }
  };

  stage(0, 0);
  __syncthreads();

  int cur = 0;
  for (int t = 0; t < nt; ++t) {
    if (t + 1 < nt) stage(cur ^ 1, t + 1);
#pragma unroll
    for (int kk = 0; kk < 2; ++kk) {
      short8 af[2], bfr[4];
#pragma unroll
      for (int mi = 0; mi < 2; ++mi) {
        const int r = wr * 32 + mi * 16 + lm;
        af[mi] = *reinterpret_cast<const short8*>(&Al[cur][r * BK + (((kk * 4 + lg) ^ XM(r)) * 8)]);
      }
#pragma unroll
      for (int ni = 0; ni < 4; ++ni) {
        const int r = wc * 64 + ni * 16 + lm;
        bfr[ni] = *reinterpret_cast<const short8*>(&Bl[cur][r * BK + (((kk * 4 + lg) ^ XM(r)) * 8)]);
      }
#pragma unroll
      for (int mi = 0; mi < 2; ++mi)
#pragma unroll
        for (int ni = 0; ni < 4; ++ni)
          acc[mi][ni] = __builtin_amdgcn_mfma_f32_16x16x32_bf16(af[mi], bfr[ni], acc[mi][ni], 0, 0, 0);
    }
    __syncthreads();
    cur ^= 1;
  }

#pragma unroll
  for (int mi = 0; mi < 2; ++mi) {
#pragma unroll
    for (int ni = 0; ni < 4; ++ni) {
      const int col = bn + wc * 64 + ni * 16 + lm;
#pragma unroll
      for (int r = 0; r < 4; ++r) {
        const int row = bm + wr * 32 + mi * 16 + lg * 4 + r;
        Cv[(size_t)row * N + col] = acc[mi][ni][r];
      }
    }
  }
}

// ---------------- causal GQA flash attention ----------------
// QBLK=128 (8 waves x 16 rows), KVBLK=64: staging bytes per output row HALVED
// vs QBLK=64. Paired q-tiles qtA in 0..7, qtB=15-qtA -> every block exactly
// 34 KV-tiles; grid (8,32)=256 uniform blocks, 1/CU, 8 waves/CU.
// K/V double-buffer prefetch, one __syncthreads per tile. LDS 80KB.
#define KVBLK 64

__global__ __launch_bounds__(512, 2) void attn_fwd(const uint16_t* __restrict__ Qb,
                                                   const uint16_t* __restrict__ Kb,
                                                   const uint16_t* __restrict__ VtG,
                                                   uint16_t* __restrict__ Ab) {
  __shared__ __align__(16) uint16_t Kl[2][KVBLK * D_];    // 32768 B
  __shared__ __align__(16) uint16_t Vtl[2][D_ * KVBLK];   // 32768 B
  __shared__ __align__(16) uint16_t Pl[8 * 16 * 64];      // 16384 B (total 81920)
  const int tid = threadIdx.x;
  const int w = tid >> 6, lane = tid & 63;   // 8 waves x 16 rows = 128 q-rows
  const int lm = lane & 15, lg = lane >> 4;
  const int bh = blockIdx.y;
  const int b = bh >> 4, h = bh & 15;
  const int kvh = h >> 2;
  const int qtA = (blockIdx.x + bh) & 7;     // q-tile of 128 rows, 0..15
  const int qtB = 15 - qtA;
  const int nA = 2 * qtA + 2;                // KVBLK-64 tiles for phase A
  const int ntot = 34;                       // nA + nB == 34 always

  const uint16_t* Kbase = Kb + ((size_t)(b * KVH_ + kvh)) * T_ * D_;
  const uint16_t* Vtbase = VtG + ((size_t)(b * KVH_ + kvh)) * D_ * T_;
  uint16_t* Pw = Pl + w * 16 * 64;
  const f32x4 z4 = {0.f, 0.f, 0.f, 0.f};

  short8 vone;
#pragma unroll
  for (int j = 0; j < 8; ++j) vone[j] = (short)0x3F80;  // bf16 1.0

  f32x4 o[8];
  f32x4 osum;
  float mrow[4];
  short8 qf[4];

  auto loadQ = [&](int qt) {
    const uint16_t* Qw = Qb + (((size_t)(b * H_ + h)) * T_ + qt * 128 + w * 16) * D_;
#pragma unroll
    for (int kk = 0; kk < 4; ++kk)
      qf[kk] = *reinterpret_cast<const short8*>(Qw + (size_t)lm * D_ + kk * 32 + lg * 8);
  };
  auto resetAcc = [&]() {
#pragma unroll
    for (int f = 0; f < 8; ++f) o[f] = z4;
    osum = z4;
#pragma unroll
    for (int r = 0; r < 4; ++r) mrow[r] = -1e30f;
  };
  auto flush = [&](int qt) {
    const int wr0 = qt * 128 + w * 16;
    float rcp[4];
#pragma unroll
    for (int r = 0; r < 4; ++r) rcp[r] = 1.0f / osum[r];
#pragma unroll
    for (int f = 0; f < 8; ++f) {
      const int col = h * D_ + f * 16 + lm;
#pragma unroll
      for (int r = 0; r < 4; ++r) {
        const int trow = wr0 + lg * 4 + r;
        Ab[((size_t)(b * T_ + trow)) * (H_ * D_) + col] = f2bf(o[f][r] * rcp[r]);
      }
    }
  };
  // stage K [64 rows][16 chunks] + Vt [128 rows][8 chunks]; 2048 chunks over
  // 512 threads x 2 iters; LDS dest linear, global source XOR-swizzled.
  auto stage = [&](int buf, int kv0) {
#pragma unroll
    for (int it = 0; it < 2; ++it) {
      const int chunk = it * 512 + tid;
      {
        const int r = chunk >> 4, c16 = chunk & 15;
        const uint16_t* g = Kbase + (size_t)(kv0 + r) * D_ + ((c16 ^ XM(r)) * 8);
        __builtin_amdgcn_global_load_lds((const __attribute__((address_space(1))) unsigned int*)g,
                                         (__attribute__((address_space(3))) unsigned int*)(&Kl[buf][0] + (it * 512 + w * 64) * 8),
                                         16, 0, 0);
      }
      {
        const int dd = chunk >> 3, c8 = chunk & 7;
        const uint16_t* g = Vtbase + (size_t)dd * T_ + kv0 + ((c8 ^ XM(dd)) * 8);
        __builtin_amdgcn_global_load_lds((const __attribute__((address_space(1))) unsigned int*)g,
                                         (__attribute__((address_space(3))) unsigned int*)(&Vtl[buf][0] + (it * 512 + w * 64) * 8),
                                         16, 0, 0);
      }
    }
  };

  loadQ(qtA);
  resetAcc();
  stage(0, 0);
  __syncthreads();

  int cur = 0;
  for (int g = 0; g < ntot; ++g) {
    const bool inA = g < nA;
    const int t = inA ? g : g - nA;
    const int qt = inA ? qtA : qtB;
    const int kv0 = t * KVBLK;
    const int wrow0 = qt * 128 + w * 16;

    if (g + 1 < ntot) {
      const int gn = g + 1;
      const int kvn = (gn < nA ? gn : gn - nA) * KVBLK;
      stage(cur ^ 1, kvn);
    }

    // S = Q K^T : 4 col-frags x 4 k-frags
    f32x4 s[4];
#pragma unroll
    for (int nf = 0; nf < 4; ++nf) s[nf] = z4;
#pragma unroll
    for (int nf = 0; nf < 4; ++nf)
#pragma unroll
      for (int kk = 0; kk < 4; ++kk) {
        const int row = nf * 16 + lm;
        const short8 kf = *reinterpret_cast<const short8*>(&Kl[cur][row * D_ + (((kk * 4 + lg) ^ XM(row)) * 8)]);
        s[nf] = __builtin_amdgcn_mfma_f32_16x16x32_bf16(qf[kk], kf, s[nf], 0, 0, 0);
      }

    // causal mask (only on diagonal-intersecting tiles for this wave)
    if (kv0 + KVBLK - 1 > wrow0) {
#pragma unroll
      for (int nf = 0; nf < 4; ++nf) {
        const int colg = kv0 + nf * 16 + lm;
#pragma unroll
        for (int r = 0; r < 4; ++r) {
          const int rowg = wrow0 + lg * 4 + r;
          if (colg > rowg) s[nf][r] = -1e30f;
        }
      }
    }

    // per-lane raw tile max; lane-reduce only when defer threshold trips
    float tmax[4];
#pragma unroll
    for (int r = 0; r < 4; ++r)
      tmax[r] = fmaxf(fmaxf(s[0][r], s[1][r]), fmaxf(s[2][r], s[3][r]));
    bool grow = false;
#pragma unroll
    for (int r = 0; r < 4; ++r) grow = grow || (tmax[r] > mrow[r] + 8.f);
    if (__any((int)grow)) {
#pragma unroll
      for (int r = 0; r < 4; ++r) {
        float v = tmax[r];
        v = fmaxf(v, __shfl_xor(v, 1));
        v = fmaxf(v, __shfl_xor(v, 2));
        v = fmaxf(v, __shfl_xor(v, 4));
        v = fmaxf(v, __shfl_xor(v, 8));
        const float nm = fmaxf(mrow[r], v);
        const float al = exp2f(mrow[r] - nm);
        mrow[r] = nm;
        osum[r] *= al;
#pragma unroll
        for (int f = 0; f < 8; ++f) o[f][r] *= al;
      }
    }
    // P = exp2(S - m) -> wave-private LDS (C/D layout -> A-frag layout)
#pragma unroll
    for (int nf = 0; nf < 4; ++nf)
#pragma unroll
      for (int r = 0; r < 4; ++r) {
        const float p = exp2f(s[nf][r] - mrow[r]);
        const int prow = lg * 4 + r;
        const int pchunk = (nf * 2 + (lm >> 3)) ^ XM(prow);
        Pw[prow * 64 + pchunk * 8 + (lm & 7)] = hwbf(p);
      }
    asm volatile("s_waitcnt lgkmcnt(0)" ::: "memory");
    short8 pf[2];
#pragma unroll
    for (int ks = 0; ks < 2; ++ks)
      pf[ks] = *reinterpret_cast<const short8*>(Pw + lm * 64 + (((ks * 4 + lg) ^ XM(lm)) * 8));
    // PV + ones-column row-sum
#pragma unroll
    for (int ks = 0; ks < 2; ++ks)
      osum = __builtin_amdgcn_mfma_f32_16x16x32_bf16(pf[ks], vone, osum, 0, 0, 0);
#pragma unroll
    for (int f = 0; f < 8; ++f)
#pragma unroll
      for (int ks = 0; ks < 2; ++ks) {
        const int dd = f * 16 + lm;
        const short8 vf = *reinterpret_cast<const short8*>(&Vtl[cur][dd * KVBLK + (((ks * 4 + lg) ^ XM(dd)) * 8)]);
        o[f] = __builtin_amdgcn_mfma_f32_16x16x32_bf16(pf[ks], vf, o[f], 0, 0, 0);
      }

    __syncthreads();
    cur ^= 1;

    if (g == nA - 1) {      // seam: finish phase A, start phase B
      flush(qtA);
      loadQ(qtB);
      resetAcc();
    }
  }
  flush(qtB);
}

// ---------------- launch ----------------
extern "C" void kernel_launch(void* const* d_in, const int* in_sizes, int n_in,
                              void* d_out, int out_size, void* d_ws, size_t ws_size,
                              hipStream_t stream) {
  const float* hidden = (const float*)d_in[0];
  const float* cosp   = (const float*)d_in[1];
  const float* sinp   = (const float*)d_in[2];
  // d_in[3] = attention_mask: exactly causal, implemented in-kernel
  const float* Wq = (const float*)d_in[4];
  const float* bq = (const float*)d_in[5];
  const float* Wk = (const float*)d_in[6];
  const float* bk = (const float*)d_in[7];
  const float* Wv = (const float*)d_in[8];
  const float* bv = (const float*)d_in[9];
  const float* Wo = (const float*)d_in[10];

  char* ws = (char*)d_ws;
  uint16_t* hidb   = (uint16_t*)(ws);              // 4096x2048 bf16   16,777,216 B
  uint16_t* wqkv   = (uint16_t*)(ws + 16777216);   // 3072x2048 bf16   12,582,912 B
  uint16_t* wob    = (uint16_t*)(ws + 29360128);   // 2048x2048 bf16    8,388,608 B
  float*    biasq  = (float*)   (ws + 37748736);   // 3072 f32             12,288 B
  uint16_t* Qb     = (uint16_t*)(ws + 62926848);   // [2][16][2048][128] 16,777,216 B
  uint16_t* Kb     = (uint16_t*)(ws + 79704064);   // [2][4][2048][128]   4,194,304 B
  uint16_t* VtG    = (uint16_t*)(ws + 83898368);   // [2][4][128][2048]   4,194,304 B
  uint16_t* Ab     = (uint16_t*)(ws + 88092672);   // [2][2048][2048]   16,777,216 B

  // one merged convert pass (hidden + Wq/Wk/Wv concat + Wo + bias concat)
  cvt_all<<<18432, 256, 0, stream>>>(hidden, Wq, Wk, Wv, Wo, bq, bk, bv,
                                     hidb, wqkv, wob, biasq);
  // QKV projection with fused bias+RoPE+scatter (+V transpose) epilogue
  gemm_qkv<<<dim3(24, 32), 512, 0, stream>>>(hidb, wqkv, biasq, cosp, sinp, Qb, Kb, VtG);
  // causal GQA flash attention -> Ab [b][t][h*128+d] bf16 (paired 128-row q-tiles)
  attn_fwd<<<dim3(8, 32), 512, 0, stream>>>(Qb, Kb, VtG, Ab);
  // output projection: [4096,2048] x [2048,2048]^T -> d_out fp32
  gemm_bt<<<dim3(16, 32), 512, 0, stream>>>(Ab, wob, (float*)d_out, 4096, 2048, 2048);
}